// Round 6
// baseline (247.960 us; speedup 1.0000x reference)
//
#include <hip/hip_runtime.h>
#include <hip/hip_bf16.h>

#define BN_INV 0.9999950000375f   // 1/sqrt(1+1e-5)
#define PI_F   3.14159265358979f

typedef __attribute__((ext_vector_type(8))) short s16x8;
typedef __attribute__((ext_vector_type(4))) float f32x4;
typedef __attribute__((ext_vector_type(4))) unsigned short u16x4;

__device__ inline unsigned short f2bf(float f) {
  union { float f; unsigned u; } v; v.f = f;
  unsigned r = v.u + 0x7fffu + ((v.u >> 16) & 1u);
  return (unsigned short)(r >> 16);
}

// ---------------------------------------------------------------------------
// pack: fp32 conv weights -> bf16 packed [co][k], k = kk*Ci_pad + ci
// + transpose fc_w -> fc_wt[k][o] (fp32), + zero h4
// ---------------------------------------------------------------------------
__global__ __launch_bounds__(256) void k_pack(
    const float* __restrict__ w1, const float* __restrict__ w2,
    const float* __restrict__ w3, const float* __restrict__ w4,
    const float* __restrict__ fcw,
    unsigned short* __restrict__ w1p, unsigned short* __restrict__ w2p,
    unsigned short* __restrict__ w3p, unsigned short* __restrict__ w4p,
    float* __restrict__ fcwt, float* __restrict__ h4)
{
  int e = blockIdx.x * 256 + threadIdx.x;
  if (e < 2048) {
    int co = e >> 6, k = e & 63, kk = k >> 3, ci = k & 7;
    w1p[e] = (ci < 4 && kk < 7) ? f2bf(w1[co * 28 + ci * 7 + kk]) : (unsigned short)0;
  } else if (e < 16384) {
    int t = e - 2048; int co = t / 224, k = t % 224, kk = k >> 5, ci = k & 31;
    w2p[t] = f2bf(w2[co * 224 + ci * 7 + kk]);
  } else if (e < 73728) {
    int t = e - 16384; int co = t / 448, k = t % 448, kk = k >> 6, ci = k & 63;
    w3p[t] = f2bf(w3[co * 448 + ci * 7 + kk]);
  } else if (e < 188416) {
    int t = e - 73728; int co = t / 896, k = t % 896, kk = k >> 7, ci = k & 127;
    w4p[t] = f2bf(w4[co * 896 + ci * 7 + kk]);
  } else if (e < 221184) {
    h4[e - 188416] = 0.f;
  } else if (e < 237568) {
    int t = e - 221184; int k = t >> 7, o = t & 127;
    fcwt[t] = fcw[o * 128 + k];
  }
}

// ---------------------------------------------------------------------------
// conv1 MFMA: x fp32 (256,4,3000) -> h1t bf16 [b][3000][32], BN+ReLU
// ---------------------------------------------------------------------------
__global__ __launch_bounds__(256) void k_conv1(
    const float* __restrict__ x, const unsigned short* __restrict__ w1p,
    const float* __restrict__ cb, const float* __restrict__ bng,
    const float* __restrict__ bnb, unsigned short* __restrict__ h1t)
{
  __shared__ __align__(16) char lds[520 * 16 + 4096 + 256];
  float* scs = (float*)(lds + 520 * 16 + 4096);
  const int tid = threadIdx.x;
  const int b = blockIdx.y;
  const int l0 = blockIdx.x * 512;

  for (int r = tid; r < 519; r += 256) {
    int gr = l0 + r - 3;
    s16x8 v;
    if (gr >= 0 && gr < 3000) {
      const float* xr = x + b * 4 * 3000 + gr;
      v[0] = (short)f2bf(xr[0]);
      v[1] = (short)f2bf(xr[3000]);
      v[2] = (short)f2bf(xr[6000]);
      v[3] = (short)f2bf(xr[9000]);
      v[4] = 0; v[5] = 0; v[6] = 0; v[7] = 0;
    } else {
      for (int i = 0; i < 8; ++i) v[i] = 0;
    }
    *(s16x8*)(lds + r * 16) = v;
  }
  {
    int co = tid >> 3, c = tid & 7;
    s16x8 v = *(const s16x8*)(w1p + co * 64 + c * 8);
    *(s16x8*)(lds + 8320 + ((co * 128 + c * 16) ^ ((co & 7) << 4))) = v;
  }
  if (tid < 32) {
    float sc = bng[tid] * BN_INV;
    scs[tid * 2] = sc;
    scs[tid * 2 + 1] = fmaf(cb[tid], sc, bnb[tid]);
  }
  __syncthreads();

  const int w = tid >> 6, l = tid & 63, lr = l & 15, g = l >> 4;
  const int wp = w * 128;
  f32x4 acc[2][8];
  for (int m = 0; m < 2; ++m)
    for (int n = 0; n < 8; ++n)
      for (int i = 0; i < 4; ++i) acc[m][n][i] = 0.f;

  #pragma unroll
  for (int s = 0; s < 2; ++s) {
    s16x8 a[2], bf[8];
    #pragma unroll
    for (int m = 0; m < 2; ++m) {
      int co = m * 16 + lr;
      a[m] = *(const s16x8*)(lds + 8320 + ((co * 128 + s * 64 + g * 16) ^ ((co & 7) << 4)));
    }
    #pragma unroll
    for (int n = 0; n < 8; ++n) {
      int row = wp + n * 16 + lr + s * 4 + g;
      bf[n] = *(const s16x8*)(lds + row * 16);
    }
    #pragma unroll
    for (int m = 0; m < 2; ++m)
      #pragma unroll
      for (int n = 0; n < 8; ++n)
        acc[m][n] = __builtin_amdgcn_mfma_f32_16x16x32_bf16(a[m], bf[n], acc[m][n], 0, 0, 0);
  }

  #pragma unroll
  for (int m = 0; m < 2; ++m) {
    int co0 = m * 16 + g * 4;
    float sc[4], sh[4];
    #pragma unroll
    for (int j = 0; j < 4; ++j) { sc[j] = scs[(co0 + j) * 2]; sh[j] = scs[(co0 + j) * 2 + 1]; }
    #pragma unroll
    for (int n = 0; n < 8; ++n) {
      int gp = l0 + wp + n * 16 + lr;
      if (gp < 3000) {
        u16x4 o;
        #pragma unroll
        for (int j = 0; j < 4; ++j)
          o[j] = f2bf(fmaxf(fmaf(acc[m][n][j], sc[j], sh[j]), 0.f));
        *(u16x4*)(h1t + (b * 3000 + gp) * 32 + co0) = o;
      }
    }
  }
}

// ---------------------------------------------------------------------------
// conv2 MFMA (operand-swapped): h1t -> BN+ReLU+pool4 -> h2pt [b][750][64]
// grid (12, 256); block: pos256 x co64; wave = pos64(4m) x co64(4n); K=224
// ---------------------------------------------------------------------------
__global__ __launch_bounds__(256) void k_conv2(
    const unsigned short* __restrict__ h1t, const unsigned short* __restrict__ w2p,
    const float* __restrict__ cb, const float* __restrict__ bng,
    const float* __restrict__ bnb, unsigned short* __restrict__ h2pt)
{
  __shared__ __align__(16) char lds[46080];
  float* scs = (float*)(lds + 45568);
  const int tid = threadIdx.x, b = blockIdx.y;
  const int l0 = blockIdx.x * 256;

  for (int e = tid; e < 1048; e += 256) {  // x: 262 rows x 4 chunks
    int r = e >> 2, c = e & 3;
    int gr = l0 + r - 3;
    s16x8 v;
    if (gr >= 0 && gr < 3000) v = *(const s16x8*)(h1t + (b * 3000 + gr) * 32 + c * 8);
    else for (int i = 0; i < 8; ++i) v[i] = 0;
    *(s16x8*)(lds + ((r * 64 + c * 16) ^ ((r & 7) << 4))) = v;
  }
  for (int e = tid; e < 1792; e += 256) {  // weights: 64co x 28 chunks
    int co = e / 28, c = e % 28;
    s16x8 v = *(const s16x8*)(w2p + co * 224 + c * 8);
    *(s16x8*)(lds + 16896 + ((co * 448 + c * 16) ^ ((co & 7) << 4))) = v;
  }
  if (tid < 64) {
    float sc = bng[tid] * BN_INV;
    scs[tid * 2] = sc;
    scs[tid * 2 + 1] = fmaf(cb[tid], sc, bnb[tid]);
  }
  __syncthreads();

  const int w = tid >> 6, l = tid & 63, lr = l & 15, g = l >> 4;
  const int wp = w * 64;
  f32x4 acc[4][4];
  for (int m = 0; m < 4; ++m)
    for (int n = 0; n < 4; ++n)
      for (int i = 0; i < 4; ++i) acc[m][n][i] = 0.f;

  #pragma unroll
  for (int s = 0; s < 7; ++s) {
    s16x8 xa[4], wb[4];
    #pragma unroll
    for (int m = 0; m < 4; ++m) {
      int row = wp + m * 16 + lr + s;
      xa[m] = *(const s16x8*)(lds + ((row * 64 + g * 16) ^ ((row & 7) << 4)));
    }
    #pragma unroll
    for (int n = 0; n < 4; ++n) {
      int co = n * 16 + lr;
      wb[n] = *(const s16x8*)(lds + 16896 + ((co * 448 + s * 64 + g * 16) ^ ((co & 7) << 4)));
    }
    #pragma unroll
    for (int m = 0; m < 4; ++m)
      #pragma unroll
      for (int n = 0; n < 4; ++n)
        acc[m][n] = __builtin_amdgcn_mfma_f32_16x16x32_bf16(xa[m], wb[n], acc[m][n], 0, 0, 0);
  }

  float sc[4], sh[4];
  #pragma unroll
  for (int n = 0; n < 4; ++n) {
    sc[n] = scs[(n * 16 + lr) * 2];
    sh[n] = scs[(n * 16 + lr) * 2 + 1];
  }
  #pragma unroll
  for (int m = 0; m < 4; ++m) {
    int pp = (l0 + wp + m * 16 + g * 4) >> 2;
    if (pp < 750) {
      unsigned short* orow = h2pt + (b * 750 + pp) * 64 + lr;
      #pragma unroll
      for (int n = 0; n < 4; ++n) {
        float v = fmaxf(fmaxf(acc[m][n][0], acc[m][n][1]),
                        fmaxf(acc[m][n][2], acc[m][n][3]));
        orow[n * 16] = f2bf(fmaxf(fmaf(v, sc[n], sh[n]), 0.f));
      }
    }
  }
}

// ---------------------------------------------------------------------------
// conv3 v2: pos128 x co128 block; wave = pos64(4m) x co64(4n); K=448, 2 chunks
// T14 reg-prefetch of chunk 1 weights. grid (6, 256)
// ---------------------------------------------------------------------------
__global__ __launch_bounds__(256) void k_conv3(
    const unsigned short* __restrict__ h2pt, const unsigned short* __restrict__ w3p,
    const float* __restrict__ cb, const float* __restrict__ bng,
    const float* __restrict__ bnb, unsigned short* __restrict__ h3pt)
{
  __shared__ __align__(16) char lds[75776];
  float* scs = (float*)(lds + 74752);
  const int tid = threadIdx.x, b = blockIdx.y;
  const int l0 = blockIdx.x * 128;

  for (int e = tid; e < 1072; e += 256) {  // x: 134 rows x 8 chunks
    int r = e >> 3, c = e & 7;
    int gr = l0 + r - 3;
    s16x8 v;
    if (gr >= 0 && gr < 750) v = *(const s16x8*)(h2pt + (b * 750 + gr) * 64 + c * 8);
    else for (int i = 0; i < 8; ++i) v[i] = 0;
    *(s16x8*)(lds + ((r * 128 + c * 16) ^ ((r & 7) << 4))) = v;
  }
  for (int e = tid; e < 3584; e += 256) {  // weights chunk 0: 128co x 28 chunks
    int co = e / 28, c = e % 28;
    s16x8 v = *(const s16x8*)(w3p + co * 448 + c * 8);
    *(s16x8*)(lds + 17408 + ((co * 448 + c * 16) ^ ((co & 7) << 4))) = v;
  }
  if (tid < 128) {
    float sc = bng[tid] * BN_INV;
    scs[tid * 2] = sc;
    scs[tid * 2 + 1] = fmaf(cb[tid], sc, bnb[tid]);
  }

  const int lane = tid & 63, wid = tid >> 6;
  const int wr = wid >> 1, wc = wid & 1;
  const int lr = lane & 15, g = lane >> 4;

  f32x4 acc[4][4];
  for (int m = 0; m < 4; ++m)
    for (int n = 0; n < 4; ++n)
      for (int i = 0; i < 4; ++i) acc[m][n][i] = 0.f;

  s16x8 pw[14];  // T14: prefetch chunk-1 weights
  #pragma unroll
  for (int i = 0; i < 14; ++i) {
    int e = tid + i * 256;
    int co = e / 28, c = e % 28;
    pw[i] = *(const s16x8*)(w3p + co * 448 + 224 + c * 8);
  }
  __syncthreads();

  for (int chunk = 0; chunk < 2; ++chunk) {
    #pragma unroll
    for (int sl = 0; sl < 7; ++sl) {
      int k0 = chunk * 224 + sl * 32;
      int kk = k0 >> 6, cib = k0 & 63;
      s16x8 xa[4], wb[4];
      #pragma unroll
      for (int m = 0; m < 4; ++m) {
        int row = wr * 64 + m * 16 + lr + kk;
        xa[m] = *(const s16x8*)(lds + ((row * 128 + cib * 2 + g * 16) ^ ((row & 7) << 4)));
      }
      #pragma unroll
      for (int n = 0; n < 4; ++n) {
        int co = wc * 64 + n * 16 + lr;
        wb[n] = *(const s16x8*)(lds + 17408 + ((co * 448 + sl * 64 + g * 16) ^ ((co & 7) << 4)));
      }
      #pragma unroll
      for (int m = 0; m < 4; ++m)
        #pragma unroll
        for (int n = 0; n < 4; ++n)
          acc[m][n] = __builtin_amdgcn_mfma_f32_16x16x32_bf16(xa[m], wb[n], acc[m][n], 0, 0, 0);
    }
    if (chunk == 0) {
      __syncthreads();
      #pragma unroll
      for (int i = 0; i < 14; ++i) {
        int e = tid + i * 256;
        int co = e / 28, c = e % 28;
        *(s16x8*)(lds + 17408 + ((co * 448 + c * 16) ^ ((co & 7) << 4))) = pw[i];
      }
      __syncthreads();
    }
  }

  float sc[4], sh[4];
  #pragma unroll
  for (int n = 0; n < 4; ++n) {
    int co = wc * 64 + n * 16 + lr;
    sc[n] = scs[co * 2];
    sh[n] = scs[co * 2 + 1];
  }
  #pragma unroll
  for (int m = 0; m < 4; ++m) {
    int pp = (l0 + wr * 64 + m * 16 + g * 4) >> 2;
    if (pp < 187) {
      unsigned short* orow = h3pt + (b * 187 + pp) * 128;
      #pragma unroll
      for (int n = 0; n < 4; ++n) {
        int co = wc * 64 + n * 16 + lr;
        float v = fmaxf(fmaxf(acc[m][n][0], acc[m][n][1]),
                        fmaxf(acc[m][n][2], acc[m][n][3]));
        orow[co] = f2bf(fmaxf(fmaf(v, sc[n], sh[n]), 0.f));
      }
    }
  }
}

// ---------------------------------------------------------------------------
// conv4 (operand-swapped): h3pt -> BN+ReLU -> masked mean -> atomicAdd h4
// ---------------------------------------------------------------------------
__global__ __launch_bounds__(256) void k_conv4(
    const unsigned short* __restrict__ h3pt, const unsigned short* __restrict__ w4p,
    const float* __restrict__ cb, const float* __restrict__ bng,
    const float* __restrict__ bnb, float* __restrict__ h4)
{
  __shared__ __align__(16) char lds[79872];
  float* scs = (float*)(lds + 79360);
  const int tid = threadIdx.x, b = blockIdx.y, ch = blockIdx.x;
  const int cg0 = ch * 64;

  #pragma unroll
  for (int i = 0; i < 13; ++i) {  // x: 198 rows x 16 chunks
    int e = tid + i * 256;
    if (e < 3168) {
      int r = e >> 4, c = e & 15, gr = r - 3;
      s16x8 v;
      if (gr >= 0 && gr < 187) v = *(const s16x8*)(h3pt + (b * 187 + gr) * 128 + c * 8);
      else for (int q = 0; q < 8; ++q) v[q] = 0;
      *(s16x8*)(lds + ((r * 256 + c * 16) ^ ((r & 7) << 4))) = v;
    }
  }
  for (int e = tid; e < 1792; e += 256) {  // weight chunk 0
    int co = e / 28, c = e % 28;
    s16x8 v = *(const s16x8*)(w4p + (cg0 + co) * 896 + c * 8);
    *(s16x8*)(lds + 50688 + ((co * 448 + c * 16) ^ ((co & 7) << 4))) = v;
  }
  if (tid < 64) {
    int co = cg0 + tid;
    float sc = bng[co] * BN_INV;
    scs[tid * 2] = sc;
    scs[tid * 2 + 1] = fmaf(cb[co], sc, bnb[co]);
  }
  __syncthreads();

  const int w = tid >> 6, l = tid & 63, lr = l & 15, g = l >> 4;
  const int wp = w * 48;

  f32x4 acc[3][4];
  for (int m = 0; m < 3; ++m)
    for (int n = 0; n < 4; ++n)
      for (int i = 0; i < 4; ++i) acc[m][n][i] = 0.f;

  for (int chunk = 0; chunk < 4; ++chunk) {
    s16x8 wr[7];
    if (chunk < 3) {
      #pragma unroll
      for (int i = 0; i < 7; ++i) {
        int e = tid + i * 256;
        int co = e / 28, c = e % 28;
        wr[i] = *(const s16x8*)(w4p + (cg0 + co) * 896 + (chunk + 1) * 224 + c * 8);
      }
    }
    #pragma unroll
    for (int sl = 0; sl < 7; ++sl) {
      int k0 = chunk * 224 + sl * 32;
      int kk = k0 >> 7, cib = k0 & 127;
      s16x8 xa[3], wb[4];
      #pragma unroll
      for (int m = 0; m < 3; ++m) {
        int row = wp + m * 16 + lr + kk;
        xa[m] = *(const s16x8*)(lds + ((row * 256 + cib * 2 + g * 16) ^ ((row & 7) << 4)));
      }
      #pragma unroll
      for (int n = 0; n < 4; ++n) {
        int co = n * 16 + lr;
        wb[n] = *(const s16x8*)(lds + 50688 + ((co * 448 + sl * 64 + g * 16) ^ ((co & 7) << 4)));
      }
      #pragma unroll
      for (int m = 0; m < 3; ++m)
        #pragma unroll
        for (int n = 0; n < 4; ++n)
          acc[m][n] = __builtin_amdgcn_mfma_f32_16x16x32_bf16(xa[m], wb[n], acc[m][n], 0, 0, 0);
    }
    __syncthreads();
    if (chunk < 3) {
      #pragma unroll
      for (int i = 0; i < 7; ++i) {
        int e = tid + i * 256;
        int co = e / 28, c = e % 28;
        *(s16x8*)(lds + 50688 + ((co * 448 + c * 16) ^ ((co & 7) << 4))) = wr[i];
      }
    }
    __syncthreads();
  }

  float sc[4], sh[4];
  #pragma unroll
  for (int n = 0; n < 4; ++n) {
    sc[n] = scs[(n * 16 + lr) * 2];
    sh[n] = scs[(n * 16 + lr) * 2 + 1];
  }
  float psum[4] = {0.f, 0.f, 0.f, 0.f};
  #pragma unroll
  for (int m = 0; m < 3; ++m) {
    #pragma unroll
    for (int j = 0; j < 4; ++j) {
      int pos = wp + m * 16 + g * 4 + j;
      if (pos < 187) {
        #pragma unroll
        for (int n = 0; n < 4; ++n)
          psum[n] += fmaxf(fmaf(acc[m][n][j], sc[n], sh[n]), 0.f);
      }
    }
  }
  #pragma unroll
  for (int n = 0; n < 4; ++n) {
    float v = psum[n];
    v += __shfl_xor(v, 16);
    v += __shfl_xor(v, 32);
    if (l < 16)
      atomicAdd(&h4[b * 128 + cg0 + n * 16 + lr], v);
  }
}

// ---------------------------------------------------------------------------
// k_umat: build U_SEL (fixed 256x256 complex unitary of the SEL layers)
// stored as Ut[col][row] float2. 16 blocks x 256 thr = 64 waves;
// wave = 4 columns; 16 lanes/col; 16 amps/lane (bits 7-4 = ll, 3-0 = reg)
// ---------------------------------------------------------------------------
__global__ __launch_bounds__(256) void k_umat(
    const float* __restrict__ qw, float2* __restrict__ Ut)
{
  __shared__ float rotm[16][8];
  const int tid = threadIdx.x;
  if (tid < 16) {
    int gq = tid;
    float phi = qw[gq * 3], th = qw[gq * 3 + 1], om = qw[gq * 3 + 2];
    float cm = cosf(0.5f * th), sm = sinf(0.5f * th);
    float ap = 0.5f * (phi + om), bm = 0.5f * (phi - om);
    rotm[gq][0] = cm * cosf(ap);  rotm[gq][1] = -cm * sinf(ap);
    rotm[gq][2] = -sm * cosf(bm); rotm[gq][3] = -sm * sinf(bm);
    rotm[gq][4] = sm * cosf(bm);  rotm[gq][5] = -sm * sinf(bm);
    rotm[gq][6] = cm * cosf(ap);  rotm[gq][7] = cm * sinf(ap);
  }
  __syncthreads();

  const int lane = tid & 63, wid = tid >> 6;
  const int ll = lane & 15;
  const int c = (blockIdx.x * 4 + wid) * 4 + (lane >> 4);

  float2 st[16];
  #pragma unroll
  for (int r = 0; r < 16; ++r) {
    st[r].x = (ll == (c >> 4) && r == (c & 15)) ? 1.f : 0.f;
    st[r].y = 0.f;
  }

#define LOADM(G) \
  float m00x = rotm[G][0], m00y = rotm[G][1], m01x = rotm[G][2], m01y = rotm[G][3], \
        m10x = rotm[G][4], m10y = rotm[G][5], m11x = rotm[G][6], m11y = rotm[G][7];

#define ROT_REG(G, BETA) { LOADM(G) \
  _Pragma("unroll") \
  for (int r = 0; r < 16; ++r) if (!(r & BETA)) { \
    float2 A = st[r], B = st[r + BETA]; \
    st[r].x = m00x*A.x - m00y*A.y + m01x*B.x - m01y*B.y; \
    st[r].y = m00x*A.y + m00y*A.x + m01x*B.y + m01y*B.x; \
    st[r+BETA].x = m10x*A.x - m10y*A.y + m11x*B.x - m11y*B.y; \
    st[r+BETA].y = m10x*A.y + m10y*A.x + m11x*B.y + m11y*B.x; } }

#define ROT_LANE(G, LX) { LOADM(G) \
  _Pragma("unroll") \
  for (int r = 0; r < 16; ++r) { \
    float ox = __shfl_xor(st[r].x, LX); \
    float oy = __shfl_xor(st[r].y, LX); \
    bool hi = (lane & LX) != 0; \
    float a0x = hi ? ox : st[r].x, a0y = hi ? oy : st[r].y; \
    float a1x = hi ? st[r].x : ox, a1y = hi ? st[r].y : oy; \
    float cx = hi ? m10x : m00x, cy = hi ? m10y : m00y; \
    float dx = hi ? m11x : m01x, dy = hi ? m11y : m01y; \
    st[r].x = cx*a0x - cy*a0y + dx*a1x - dy*a1y; \
    st[r].y = cx*a0y + cy*a0x + dx*a1y + dy*a1x; } }

#define CNOT_RR(BC, BT) { \
  _Pragma("unroll") \
  for (int r = 0; r < 16; ++r) if ((r & BC) && !(r & BT)) { \
    float2 t_ = st[r]; st[r] = st[r + BT]; st[r + BT] = t_; } }

#define CNOT_RL(BC, LXT) { \
  _Pragma("unroll") \
  for (int r = 0; r < 16; ++r) if (r & BC) { \
    st[r].x = __shfl_xor(st[r].x, LXT); \
    st[r].y = __shfl_xor(st[r].y, LXT); } }

#define CNOT_LR(LXC, BT) { bool cc = (lane & LXC) != 0; \
  _Pragma("unroll") \
  for (int r = 0; r < 16; ++r) if (!(r & BT)) { \
    float2 A = st[r], B = st[r + BT]; \
    st[r].x = cc ? B.x : A.x;  st[r].y = cc ? B.y : A.y; \
    st[r+BT].x = cc ? A.x : B.x;  st[r+BT].y = cc ? A.y : B.y; } }

#define CNOT_LL(LXC, LXT) { bool cc = (lane & LXC) != 0; \
  _Pragma("unroll") \
  for (int r = 0; r < 16; ++r) { \
    float ox = __shfl_xor(st[r].x, LXT); \
    float oy = __shfl_xor(st[r].y, LXT); \
    if (cc) { st[r].x = ox; st[r].y = oy; } } }

  // layer 0: Rot wires 0..7; CNOT ring r=1
  ROT_LANE(0, 8) ROT_LANE(1, 4) ROT_LANE(2, 2) ROT_LANE(3, 1)
  ROT_REG(4, 8)  ROT_REG(5, 4)  ROT_REG(6, 2)  ROT_REG(7, 1)
  CNOT_LL(8, 4) CNOT_LL(4, 2) CNOT_LL(2, 1) CNOT_LR(1, 8)
  CNOT_RR(8, 4) CNOT_RR(4, 2) CNOT_RR(2, 1) CNOT_RL(1, 8)
  // layer 1: Rot wires 0..7; CNOT ring r=2
  ROT_LANE(8, 8) ROT_LANE(9, 4) ROT_LANE(10, 2) ROT_LANE(11, 1)
  ROT_REG(12, 8) ROT_REG(13, 4) ROT_REG(14, 2)  ROT_REG(15, 1)
  CNOT_LL(8, 2) CNOT_LL(4, 1) CNOT_LR(2, 8) CNOT_LR(1, 4)
  CNOT_RR(8, 2) CNOT_RR(4, 1) CNOT_RL(2, 8) CNOT_RL(1, 4)

#undef LOADM
#undef ROT_REG
#undef ROT_LANE
#undef CNOT_RR
#undef CNOT_RL
#undef CNOT_LR
#undef CNOT_LL

  float2* uc = Ut + c * 256 + ll * 16;
  #pragma unroll
  for (int r = 0; r < 16; r += 2) {
    float4 v = make_float4(st[r].x, st[r].y, st[r + 1].x, st[r + 1].y);
    *(float4*)(uc + r) = v;
  }
}

// ---------------------------------------------------------------------------
// k_head2: 64 blocks x 256 thr, 4 batches/block.
// h4 -> fc -> ang -> embed (real product state) -> out = U_SEL * e (fp32
// GEMM, coalesced Ut) -> probs -> z -> h1 -> h2 -> out
// ---------------------------------------------------------------------------
__global__ __launch_bounds__(256) void k_head2(
    const float* __restrict__ h4, const float* __restrict__ fc_wt,
    const float* __restrict__ fc_b, const float* __restrict__ ang_w,
    const float* __restrict__ ang_b, const float* __restrict__ h1_w,
    const float* __restrict__ h1_b, const float* __restrict__ h2_w,
    const float* __restrict__ h2_b, const float2* __restrict__ Ut,
    float* __restrict__ out)
{
  __shared__ float h4v[512];    // [b][k]
  __shared__ float fvec[512];   // [b][o]
  __shared__ float rcs[64];     // [b*16 + w*2 + {c,s}]
  __shared__ float4 e4[256];    // [col] -> 4 batches
  __shared__ float4 parr[256];  // [row] -> p per batch
  __shared__ float zsum[32];    // [b*8+w]
  __shared__ float hh[256];     // [b*64+o]

  const int tid = threadIdx.x;
  const int b0 = blockIdx.x * 4;

  #pragma unroll
  for (int q = 0; q < 2; ++q) {
    int task = tid + q * 256;
    h4v[task] = h4[(b0 + (task >> 7)) * 128 + (task & 127)] * (1.0f / 187.0f);
  }
  __syncthreads();

  // fc 128->128 (coalesced via transposed weights)
  #pragma unroll
  for (int q = 0; q < 2; ++q) {
    int task = tid + q * 256;
    int bb = task >> 7, o = task & 127;
    float a = fc_b[o];
    const float* hv = h4v + bb * 128;
    #pragma unroll 8
    for (int k = 0; k < 128; ++k) a = fmaf(hv[k], fc_wt[k * 128 + o], a);
    fvec[task] = fmaxf(a, 0.f);
  }
  __syncthreads();

  // ang 128->8 -> RY coefficients
  if (tid < 32) {
    int bb = tid >> 3, o = tid & 7;
    float a = ang_b[o];
    const float* fv = fvec + bb * 128;
    const float* wr = ang_w + o * 128;
    for (int k = 0; k < 128; ++k) a = fmaf(fv[k], wr[k], a);
    float ang = PI_F * tanhf(a);
    rcs[bb * 16 + o * 2]     = cosf(0.5f * ang);
    rcs[bb * 16 + o * 2 + 1] = sinf(0.5f * ang);
  }
  __syncthreads();

  // embed: e[b][col=tid] = prod_w (bit ? s : c)  (real product state)
  {
    float4 ev;
    #pragma unroll
    for (int bb = 0; bb < 4; ++bb) {
      float prod = 1.f;
      #pragma unroll
      for (int w = 0; w < 8; ++w) {
        float cc = rcs[bb * 16 + w * 2];
        float ss = rcs[bb * 16 + w * 2 + 1];
        prod *= ((tid >> (7 - w)) & 1) ? ss : cc;
      }
      ev[bb] = prod;
    }
    e4[tid] = ev;
  }
  __syncthreads();

  // GEMM: amp_out[b][row=tid] = sum_c Ut[c][row] * e[b][c]
  {
    float ax0 = 0.f, ax1 = 0.f, ax2 = 0.f, ax3 = 0.f;
    float ay0 = 0.f, ay1 = 0.f, ay2 = 0.f, ay3 = 0.f;
    #pragma unroll 4
    for (int cc = 0; cc < 256; ++cc) {
      float2 u = Ut[cc * 256 + tid];
      float4 ev = e4[cc];
      ax0 = fmaf(u.x, ev[0], ax0); ay0 = fmaf(u.y, ev[0], ay0);
      ax1 = fmaf(u.x, ev[1], ax1); ay1 = fmaf(u.y, ev[1], ay1);
      ax2 = fmaf(u.x, ev[2], ax2); ay2 = fmaf(u.y, ev[2], ay2);
      ax3 = fmaf(u.x, ev[3], ax3); ay3 = fmaf(u.y, ev[3], ay3);
    }
    parr[tid] = make_float4(ax0 * ax0 + ay0 * ay0, ax1 * ax1 + ay1 * ay1,
                            ax2 * ax2 + ay2 * ay2, ax3 * ax3 + ay3 * ay3);
  }
  __syncthreads();

  // z_w = sum_row sign * p ; 32 tasks x 8 partial threads
  {
    int task = tid >> 3, part = tid & 7;
    int bb = task >> 3, wq = task & 7;
    int bit = 7 - wq;
    float s = 0.f;
    #pragma unroll 8
    for (int i = 0; i < 32; ++i) {
      int row = i * 8 + part;
      const float* pr = (const float*)&parr[row];
      float p = pr[bb];
      s = ((row >> bit) & 1) ? (s - p) : (s + p);
    }
    s += __shfl_xor(s, 1);
    s += __shfl_xor(s, 2);
    s += __shfl_xor(s, 4);
    if (part == 0) zsum[task] = s;
  }
  __syncthreads();

  // h1: 4b x 64o
  {
    int bb = tid >> 6, o = tid & 63;
    float a = h1_b[o];
    #pragma unroll
    for (int k = 0; k < 8; ++k) a = fmaf(zsum[bb * 8 + k], h1_w[o * 8 + k], a);
    hh[tid] = fmaxf(a, 0.f);
  }
  __syncthreads();

  // h2: 4b x 5o
  if (tid < 20) {
    int bb = tid / 5, o = tid % 5;
    float a = h2_b[o];
    for (int j = 0; j < 64; ++j) a = fmaf(hh[bb * 64 + j], h2_w[o * 64 + j], a);
    out[(b0 + bb) * 5 + o] = a;
  }
}

// ---------------------------------------------------------------------------
extern "C" void kernel_launch(void* const* d_in, const int* in_sizes, int n_in,
                              void* d_out, int out_size, void* d_ws, size_t ws_size,
                              hipStream_t stream) {
  (void)in_sizes; (void)n_in; (void)out_size; (void)ws_size;
  const float* x    = (const float*)d_in[0];
  const float* c1w  = (const float*)d_in[1];
  const float* c1b  = (const float*)d_in[2];
  const float* b1g  = (const float*)d_in[3];
  const float* b1b  = (const float*)d_in[4];
  const float* c2w  = (const float*)d_in[5];
  const float* c2b  = (const float*)d_in[6];
  const float* b2g  = (const float*)d_in[7];
  const float* b2b  = (const float*)d_in[8];
  const float* c3w  = (const float*)d_in[9];
  const float* c3b  = (const float*)d_in[10];
  const float* b3g  = (const float*)d_in[11];
  const float* b3b  = (const float*)d_in[12];
  const float* c4w  = (const float*)d_in[13];
  const float* c4b  = (const float*)d_in[14];
  const float* b4g  = (const float*)d_in[15];
  const float* b4b  = (const float*)d_in[16];
  const float* fcw  = (const float*)d_in[17];
  const float* fcb  = (const float*)d_in[18];
  const float* angw = (const float*)d_in[19];
  const float* angb = (const float*)d_in[20];
  const float* qw   = (const float*)d_in[21];
  const float* h1w  = (const float*)d_in[22];
  const float* h1b  = (const float*)d_in[23];
  const float* h2w  = (const float*)d_in[24];
  const float* h2b  = (const float*)d_in[25];

  char* wsb = (char*)d_ws;
  unsigned short* w1p  = (unsigned short*)(wsb + 0);        // 4096 B
  unsigned short* w2p  = (unsigned short*)(wsb + 4096);     // 28672 B
  unsigned short* w3p  = (unsigned short*)(wsb + 32768);    // 114688 B
  unsigned short* w4p  = (unsigned short*)(wsb + 147456);   // 229376 B
  float*          h4   = (float*)(wsb + 393216);            // 131072 B
  unsigned short* h1t  = (unsigned short*)(wsb + 1048576);  // 49.15 MB
  unsigned short* h2pt = (unsigned short*)(wsb + 52428800); // 24.58 MB
  unsigned short* h3pt = (unsigned short*)(wsb + 79691776); // 12.25 MB
  float2*         Ut   = (float2*)(wsb + 100663296);        // 524288 B
  float*          fcwt = (float*)(wsb + 101187584);         // 65536 B

  k_pack<<<dim3(928), 256, 0, stream>>>(c1w, c2w, c3w, c4w, fcw,
                                        w1p, w2p, w3p, w4p, fcwt, h4);
  k_umat<<<dim3(16), 256, 0, stream>>>(qw, Ut);
  k_conv1<<<dim3(6, 256),  256, 0, stream>>>(x, w1p, c1b, b1g, b1b, h1t);
  k_conv2<<<dim3(12, 256), 256, 0, stream>>>(h1t, w2p, c2b, b2g, b2b, h2pt);
  k_conv3<<<dim3(6, 256),  256, 0, stream>>>(h2pt, w3p, c3b, b3g, b3b, h3pt);
  k_conv4<<<dim3(2, 256),  256, 0, stream>>>(h3pt, w4p, c4b, b4g, b4b, h4);
  k_head2<<<dim3(64), 256, 0, stream>>>(h4, fcwt, fcb, angw, angb,
                                        h1w, h1b, h2w, h2b, Ut, (float*)d_out);
}

// Round 7
// 237.050 us; speedup vs baseline: 1.0460x; 1.0460x over previous
//
#include <hip/hip_runtime.h>
#include <hip/hip_bf16.h>

#define BN_INV 0.9999950000375f   // 1/sqrt(1+1e-5)
#define PI_F   3.14159265358979f

typedef __attribute__((ext_vector_type(8))) short s16x8;
typedef __attribute__((ext_vector_type(4))) float f32x4;
typedef __attribute__((ext_vector_type(4))) unsigned short u16x4;

__device__ inline unsigned short f2bf(float f) {
  union { float f; unsigned u; } v; v.f = f;
  unsigned r = v.u + 0x7fffu + ((v.u >> 16) & 1u);
  return (unsigned short)(r >> 16);
}

// ---------------------------------------------------------------------------
// k_packumat: blocks 0..927 = weight pack (+h4 zero, fc transpose);
// blocks 928..943 = build U_SEL (fixed 256x256 SEL unitary), Ut[col][row]
// ---------------------------------------------------------------------------
__global__ __launch_bounds__(256) void k_packumat(
    const float* __restrict__ w1, const float* __restrict__ w2,
    const float* __restrict__ w3, const float* __restrict__ w4,
    const float* __restrict__ fcw, const float* __restrict__ qw,
    unsigned short* __restrict__ w1p, unsigned short* __restrict__ w2p,
    unsigned short* __restrict__ w3p, unsigned short* __restrict__ w4p,
    float* __restrict__ fcwt, float* __restrict__ h4,
    float2* __restrict__ Ut)
{
  __shared__ float rotm[16][8];
  const int tid = threadIdx.x;

  if (blockIdx.x < 928) {
    int e = blockIdx.x * 256 + tid;
    if (e < 2048) {
      int co = e >> 6, k = e & 63, kk = k >> 3, ci = k & 7;
      w1p[e] = (ci < 4 && kk < 7) ? f2bf(w1[co * 28 + ci * 7 + kk]) : (unsigned short)0;
    } else if (e < 16384) {
      int t = e - 2048; int co = t / 224, k = t % 224, kk = k >> 5, ci = k & 31;
      w2p[t] = f2bf(w2[co * 224 + ci * 7 + kk]);
    } else if (e < 73728) {
      int t = e - 16384; int co = t / 448, k = t % 448, kk = k >> 6, ci = k & 63;
      w3p[t] = f2bf(w3[co * 448 + ci * 7 + kk]);
    } else if (e < 188416) {
      int t = e - 73728; int co = t / 896, k = t % 896, kk = k >> 7, ci = k & 127;
      w4p[t] = f2bf(w4[co * 896 + ci * 7 + kk]);
    } else if (e < 221184) {
      h4[e - 188416] = 0.f;
    } else if (e < 237568) {
      int t = e - 221184; int k = t >> 7, o = t & 127;
      fcwt[t] = fcw[o * 128 + k];
    }
    return;
  }

  // ---- umat path ----
  const int bx = blockIdx.x - 928;
  if (tid < 16) {
    int gq = tid;
    float phi = qw[gq * 3], th = qw[gq * 3 + 1], om = qw[gq * 3 + 2];
    float cm = cosf(0.5f * th), sm = sinf(0.5f * th);
    float ap = 0.5f * (phi + om), bm = 0.5f * (phi - om);
    rotm[gq][0] = cm * cosf(ap);  rotm[gq][1] = -cm * sinf(ap);
    rotm[gq][2] = -sm * cosf(bm); rotm[gq][3] = -sm * sinf(bm);
    rotm[gq][4] = sm * cosf(bm);  rotm[gq][5] = -sm * sinf(bm);
    rotm[gq][6] = cm * cosf(ap);  rotm[gq][7] = cm * sinf(ap);
  }
  __syncthreads();

  const int lane = tid & 63, wid = tid >> 6;
  const int ll = lane & 15;
  const int c = (bx * 4 + wid) * 4 + (lane >> 4);

  float2 st[16];
  #pragma unroll
  for (int r = 0; r < 16; ++r) {
    st[r].x = (ll == (c >> 4) && r == (c & 15)) ? 1.f : 0.f;
    st[r].y = 0.f;
  }

#define LOADM(G) \
  float m00x = rotm[G][0], m00y = rotm[G][1], m01x = rotm[G][2], m01y = rotm[G][3], \
        m10x = rotm[G][4], m10y = rotm[G][5], m11x = rotm[G][6], m11y = rotm[G][7];

#define ROT_REG(G, BETA) { LOADM(G) \
  _Pragma("unroll") \
  for (int r = 0; r < 16; ++r) if (!(r & BETA)) { \
    float2 A = st[r], B = st[r + BETA]; \
    st[r].x = m00x*A.x - m00y*A.y + m01x*B.x - m01y*B.y; \
    st[r].y = m00x*A.y + m00y*A.x + m01x*B.y + m01y*B.x; \
    st[r+BETA].x = m10x*A.x - m10y*A.y + m11x*B.x - m11y*B.y; \
    st[r+BETA].y = m10x*A.y + m10y*A.x + m11x*B.y + m11y*B.x; } }

#define ROT_LANE(G, LX) { LOADM(G) \
  _Pragma("unroll") \
  for (int r = 0; r < 16; ++r) { \
    float ox = __shfl_xor(st[r].x, LX); \
    float oy = __shfl_xor(st[r].y, LX); \
    bool hi = (lane & LX) != 0; \
    float a0x = hi ? ox : st[r].x, a0y = hi ? oy : st[r].y; \
    float a1x = hi ? st[r].x : ox, a1y = hi ? st[r].y : oy; \
    float cx = hi ? m10x : m00x, cy = hi ? m10y : m00y; \
    float dx = hi ? m11x : m01x, dy = hi ? m11y : m01y; \
    st[r].x = cx*a0x - cy*a0y + dx*a1x - dy*a1y; \
    st[r].y = cx*a0y + cy*a0x + dx*a1y + dy*a1x; } }

#define CNOT_RR(BC, BT) { \
  _Pragma("unroll") \
  for (int r = 0; r < 16; ++r) if ((r & BC) && !(r & BT)) { \
    float2 t_ = st[r]; st[r] = st[r + BT]; st[r + BT] = t_; } }

#define CNOT_RL(BC, LXT) { \
  _Pragma("unroll") \
  for (int r = 0; r < 16; ++r) if (r & BC) { \
    st[r].x = __shfl_xor(st[r].x, LXT); \
    st[r].y = __shfl_xor(st[r].y, LXT); } }

#define CNOT_LR(LXC, BT) { bool cc = (lane & LXC) != 0; \
  _Pragma("unroll") \
  for (int r = 0; r < 16; ++r) if (!(r & BT)) { \
    float2 A = st[r], B = st[r + BT]; \
    st[r].x = cc ? B.x : A.x;  st[r].y = cc ? B.y : A.y; \
    st[r+BT].x = cc ? A.x : B.x;  st[r+BT].y = cc ? A.y : B.y; } }

#define CNOT_LL(LXC, LXT) { bool cc = (lane & LXC) != 0; \
  _Pragma("unroll") \
  for (int r = 0; r < 16; ++r) { \
    float ox = __shfl_xor(st[r].x, LXT); \
    float oy = __shfl_xor(st[r].y, LXT); \
    if (cc) { st[r].x = ox; st[r].y = oy; } } }

  // layer 0: Rot wires 0..7; CNOT ring r=1
  ROT_LANE(0, 8) ROT_LANE(1, 4) ROT_LANE(2, 2) ROT_LANE(3, 1)
  ROT_REG(4, 8)  ROT_REG(5, 4)  ROT_REG(6, 2)  ROT_REG(7, 1)
  CNOT_LL(8, 4) CNOT_LL(4, 2) CNOT_LL(2, 1) CNOT_LR(1, 8)
  CNOT_RR(8, 4) CNOT_RR(4, 2) CNOT_RR(2, 1) CNOT_RL(1, 8)
  // layer 1: Rot wires 0..7; CNOT ring r=2
  ROT_LANE(8, 8) ROT_LANE(9, 4) ROT_LANE(10, 2) ROT_LANE(11, 1)
  ROT_REG(12, 8) ROT_REG(13, 4) ROT_REG(14, 2)  ROT_REG(15, 1)
  CNOT_LL(8, 2) CNOT_LL(4, 1) CNOT_LR(2, 8) CNOT_LR(1, 4)
  CNOT_RR(8, 2) CNOT_RR(4, 1) CNOT_RL(2, 8) CNOT_RL(1, 4)

#undef LOADM
#undef ROT_REG
#undef ROT_LANE
#undef CNOT_RR
#undef CNOT_RL
#undef CNOT_LR
#undef CNOT_LL

  float2* uc = Ut + c * 256 + ll * 16;
  #pragma unroll
  for (int r = 0; r < 16; r += 2) {
    float4 v = make_float4(st[r].x, st[r].y, st[r + 1].x, st[r + 1].y);
    *(float4*)(uc + r) = v;
  }
}

// ---------------------------------------------------------------------------
// k_conv12: fused conv1(+BN+ReLU, in-LDS) + conv2(+BN+ReLU+pool4)
// grid (12, 256); block: pos256 x co64.
// Phase A: stage x raw (280 rows x 16B: 4ch bf16 + pad), compute h1 tile
//   (262 rows x 32ch) via MFMA into LDS (conv2 x-layout, swizzled).
// Phase B: proven conv2 (wave = pos64(4m) x co64(4n), K=224) -> h2pt.
// LDS 50816 B -> 3 blocks/CU.
// ---------------------------------------------------------------------------
__global__ __launch_bounds__(256) void k_conv12(
    const float* __restrict__ x, const unsigned short* __restrict__ w1p,
    const unsigned short* __restrict__ w2p,
    const float* __restrict__ c1b, const float* __restrict__ b1g,
    const float* __restrict__ b1b,
    const float* __restrict__ c2b, const float* __restrict__ b2g,
    const float* __restrict__ b2b,
    unsigned short* __restrict__ h2pt)
{
  __shared__ __align__(16) char lds[50816];
  const int XR = 0;          // x raw: 280 rows x 16B = 4480
  const int H1 = 4480;       // h1 tile: 264 rows x 64B = 16896
  const int W2 = 21376;      // conv2 weights: 28672
  float* s1 = (float*)(lds + 50048);  // 32 co x {scale, shift}
  float* s2 = (float*)(lds + 50304);  // 64 co x {scale, shift}

  const int tid = threadIdx.x, b = blockIdx.y;
  const int l0 = blockIdx.x * 256;

  // stage x raw: row r <-> global pos l0-6+r; rows >=268 zero (pad taps)
  for (int r = tid; r < 280; r += 256) {
    int gp = l0 - 6 + r;
    s16x8 v;
    for (int i = 0; i < 8; ++i) v[i] = 0;
    if (r < 268 && gp >= 0 && gp < 3000) {
      const float* xr = x + b * 4 * 3000 + gp;
      v[0] = (short)f2bf(xr[0]);
      v[1] = (short)f2bf(xr[3000]);
      v[2] = (short)f2bf(xr[6000]);
      v[3] = (short)f2bf(xr[9000]);
    }
    *(s16x8*)(lds + XR + r * 16) = v;
  }
  for (int e = tid; e < 1792; e += 256) {  // conv2 weights: 64co x 28 chunks
    int co = e / 28, cc = e % 28;
    s16x8 v = *(const s16x8*)(w2p + co * 224 + cc * 8);
    *(s16x8*)(lds + W2 + ((co * 448 + cc * 16) ^ ((co & 7) << 4))) = v;
  }
  if (tid < 32) {
    float sc = b1g[tid] * BN_INV;
    s1[tid * 2] = sc;
    s1[tid * 2 + 1] = fmaf(c1b[tid], sc, b1b[tid]);
  }
  if (tid < 64) {
    float sc = b2g[tid] * BN_INV;
    s2[tid * 2] = sc;
    s2[tid * 2 + 1] = fmaf(c2b[tid], sc, b2b[tid]);
  }
  __syncthreads();

  const int w = tid >> 6, lane = tid & 63, lr = lane & 15, g = lane >> 4;

  // ---- Phase A: conv1 -> h1 LDS tile ----
  {
    s16x8 a1[2][2];
    #pragma unroll
    for (int m = 0; m < 2; ++m)
      #pragma unroll
      for (int s = 0; s < 2; ++s)
        a1[m][s] = *(const s16x8*)(w1p + (m * 16 + lr) * 64 + s * 32 + g * 8);

    #pragma unroll
    for (int t = 0; t < 5; ++t) {
      int tile = w + t * 4;             // 17 tiles cover 272 >= 262 rows
      if (tile >= 17) break;
      int p0 = tile * 16;
      f32x4 acc[2];
      for (int m = 0; m < 2; ++m)
        for (int i = 0; i < 4; ++i) acc[m][i] = 0.f;
      #pragma unroll
      for (int s = 0; s < 2; ++s) {
        s16x8 bf = *(const s16x8*)(lds + XR + (p0 + lr + s * 4 + g) * 16);
        acc[0] = __builtin_amdgcn_mfma_f32_16x16x32_bf16(a1[0][s], bf, acc[0], 0, 0, 0);
        acc[1] = __builtin_amdgcn_mfma_f32_16x16x32_bf16(a1[1][s], bf, acc[1], 0, 0, 0);
      }
      int r2 = p0 + lr;                 // h1 tile row (pos)
      if (r2 < 262) {
        #pragma unroll
        for (int m = 0; m < 2; ++m) {
          int co0 = m * 16 + g * 4;
          u16x4 o;
          #pragma unroll
          for (int j = 0; j < 4; ++j)
            o[j] = f2bf(fmaxf(fmaf(acc[m][j], s1[(co0 + j) * 2], s1[(co0 + j) * 2 + 1]), 0.f));
          int byte = ((r2 * 64 + (co0 >> 3) * 16) ^ ((r2 & 7) << 4)) + (co0 & 7) * 2;
          *(u16x4*)(lds + H1 + byte) = o;
        }
      }
    }
  }
  __syncthreads();

  // ---- Phase B: conv2 + pool4 (proven structure) ----
  const int wp = w * 64;
  f32x4 acc[4][4];
  for (int m = 0; m < 4; ++m)
    for (int n = 0; n < 4; ++n)
      for (int i = 0; i < 4; ++i) acc[m][n][i] = 0.f;

  #pragma unroll
  for (int s = 0; s < 7; ++s) {
    s16x8 xa[4], wb[4];
    #pragma unroll
    for (int m = 0; m < 4; ++m) {
      int row = wp + m * 16 + lr + s;
      xa[m] = *(const s16x8*)(lds + H1 + ((row * 64 + g * 16) ^ ((row & 7) << 4)));
    }
    #pragma unroll
    for (int n = 0; n < 4; ++n) {
      int co = n * 16 + lr;
      wb[n] = *(const s16x8*)(lds + W2 + ((co * 448 + s * 64 + g * 16) ^ ((co & 7) << 4)));
    }
    #pragma unroll
    for (int m = 0; m < 4; ++m)
      #pragma unroll
      for (int n = 0; n < 4; ++n)
        acc[m][n] = __builtin_amdgcn_mfma_f32_16x16x32_bf16(xa[m], wb[n], acc[m][n], 0, 0, 0);
  }

  float sc[4], sh[4];
  #pragma unroll
  for (int n = 0; n < 4; ++n) {
    sc[n] = s2[(n * 16 + lr) * 2];
    sh[n] = s2[(n * 16 + lr) * 2 + 1];
  }
  #pragma unroll
  for (int m = 0; m < 4; ++m) {
    int pp = (l0 + wp + m * 16 + g * 4) >> 2;
    if (pp < 750) {
      unsigned short* orow = h2pt + (b * 750 + pp) * 64 + lr;
      #pragma unroll
      for (int n = 0; n < 4; ++n) {
        float v = fmaxf(fmaxf(acc[m][n][0], acc[m][n][1]),
                        fmaxf(acc[m][n][2], acc[m][n][3]));
        orow[n * 16] = f2bf(fmaxf(fmaf(v, sc[n], sh[n]), 0.f));
      }
    }
  }
}

// ---------------------------------------------------------------------------
// conv3 v2: pos128 x co128 block; wave = pos64(4m) x co64(4n); K=448, 2 chunks
// T14 reg-prefetch of chunk 1 weights. grid (6, 256)
// ---------------------------------------------------------------------------
__global__ __launch_bounds__(256) void k_conv3(
    const unsigned short* __restrict__ h2pt, const unsigned short* __restrict__ w3p,
    const float* __restrict__ cb, const float* __restrict__ bng,
    const float* __restrict__ bnb, unsigned short* __restrict__ h3pt)
{
  __shared__ __align__(16) char lds[75776];
  float* scs = (float*)(lds + 74752);
  const int tid = threadIdx.x, b = blockIdx.y;
  const int l0 = blockIdx.x * 128;

  for (int e = tid; e < 1072; e += 256) {  // x: 134 rows x 8 chunks
    int r = e >> 3, c = e & 7;
    int gr = l0 + r - 3;
    s16x8 v;
    if (gr >= 0 && gr < 750) v = *(const s16x8*)(h2pt + (b * 750 + gr) * 64 + c * 8);
    else for (int i = 0; i < 8; ++i) v[i] = 0;
    *(s16x8*)(lds + ((r * 128 + c * 16) ^ ((r & 7) << 4))) = v;
  }
  for (int e = tid; e < 3584; e += 256) {  // weights chunk 0: 128co x 28 chunks
    int co = e / 28, c = e % 28;
    s16x8 v = *(const s16x8*)(w3p + co * 448 + c * 8);
    *(s16x8*)(lds + 17408 + ((co * 448 + c * 16) ^ ((co & 7) << 4))) = v;
  }
  if (tid < 128) {
    float sc = bng[tid] * BN_INV;
    scs[tid * 2] = sc;
    scs[tid * 2 + 1] = fmaf(cb[tid], sc, bnb[tid]);
  }

  const int lane = tid & 63, wid = tid >> 6;
  const int wr = wid >> 1, wc = wid & 1;
  const int lr = lane & 15, g = lane >> 4;

  f32x4 acc[4][4];
  for (int m = 0; m < 4; ++m)
    for (int n = 0; n < 4; ++n)
      for (int i = 0; i < 4; ++i) acc[m][n][i] = 0.f;

  s16x8 pw[14];  // T14: prefetch chunk-1 weights
  #pragma unroll
  for (int i = 0; i < 14; ++i) {
    int e = tid + i * 256;
    int co = e / 28, c = e % 28;
    pw[i] = *(const s16x8*)(w3p + co * 448 + 224 + c * 8);
  }
  __syncthreads();

  for (int chunk = 0; chunk < 2; ++chunk) {
    #pragma unroll
    for (int sl = 0; sl < 7; ++sl) {
      int k0 = chunk * 224 + sl * 32;
      int kk = k0 >> 6, cib = k0 & 63;
      s16x8 xa[4], wb[4];
      #pragma unroll
      for (int m = 0; m < 4; ++m) {
        int row = wr * 64 + m * 16 + lr + kk;
        xa[m] = *(const s16x8*)(lds + ((row * 128 + cib * 2 + g * 16) ^ ((row & 7) << 4)));
      }
      #pragma unroll
      for (int n = 0; n < 4; ++n) {
        int co = wc * 64 + n * 16 + lr;
        wb[n] = *(const s16x8*)(lds + 17408 + ((co * 448 + sl * 64 + g * 16) ^ ((co & 7) << 4)));
      }
      #pragma unroll
      for (int m = 0; m < 4; ++m)
        #pragma unroll
        for (int n = 0; n < 4; ++n)
          acc[m][n] = __builtin_amdgcn_mfma_f32_16x16x32_bf16(xa[m], wb[n], acc[m][n], 0, 0, 0);
    }
    if (chunk == 0) {
      __syncthreads();
      #pragma unroll
      for (int i = 0; i < 14; ++i) {
        int e = tid + i * 256;
        int co = e / 28, c = e % 28;
        *(s16x8*)(lds + 17408 + ((co * 448 + c * 16) ^ ((co & 7) << 4))) = pw[i];
      }
      __syncthreads();
    }
  }

  float sc[4], sh[4];
  #pragma unroll
  for (int n = 0; n < 4; ++n) {
    int co = wc * 64 + n * 16 + lr;
    sc[n] = scs[co * 2];
    sh[n] = scs[co * 2 + 1];
  }
  #pragma unroll
  for (int m = 0; m < 4; ++m) {
    int pp = (l0 + wr * 64 + m * 16 + g * 4) >> 2;
    if (pp < 187) {
      unsigned short* orow = h3pt + (b * 187 + pp) * 128;
      #pragma unroll
      for (int n = 0; n < 4; ++n) {
        int co = wc * 64 + n * 16 + lr;
        float v = fmaxf(fmaxf(acc[m][n][0], acc[m][n][1]),
                        fmaxf(acc[m][n][2], acc[m][n][3]));
        orow[co] = f2bf(fmaxf(fmaf(v, sc[n], sh[n]), 0.f));
      }
    }
  }
}

// ---------------------------------------------------------------------------
// conv4 (operand-swapped): h3pt -> BN+ReLU -> masked mean -> atomicAdd h4
// ---------------------------------------------------------------------------
__global__ __launch_bounds__(256) void k_conv4(
    const unsigned short* __restrict__ h3pt, const unsigned short* __restrict__ w4p,
    const float* __restrict__ cb, const float* __restrict__ bng,
    const float* __restrict__ bnb, float* __restrict__ h4)
{
  __shared__ __align__(16) char lds[79872];
  float* scs = (float*)(lds + 79360);
  const int tid = threadIdx.x, b = blockIdx.y, ch = blockIdx.x;
  const int cg0 = ch * 64;

  #pragma unroll
  for (int i = 0; i < 13; ++i) {  // x: 198 rows x 16 chunks
    int e = tid + i * 256;
    if (e < 3168) {
      int r = e >> 4, c = e & 15, gr = r - 3;
      s16x8 v;
      if (gr >= 0 && gr < 187) v = *(const s16x8*)(h3pt + (b * 187 + gr) * 128 + c * 8);
      else for (int q = 0; q < 8; ++q) v[q] = 0;
      *(s16x8*)(lds + ((r * 256 + c * 16) ^ ((r & 7) << 4))) = v;
    }
  }
  for (int e = tid; e < 1792; e += 256) {  // weight chunk 0
    int co = e / 28, c = e % 28;
    s16x8 v = *(const s16x8*)(w4p + (cg0 + co) * 896 + c * 8);
    *(s16x8*)(lds + 50688 + ((co * 448 + c * 16) ^ ((co & 7) << 4))) = v;
  }
  if (tid < 64) {
    int co = cg0 + tid;
    float sc = bng[co] * BN_INV;
    scs[tid * 2] = sc;
    scs[tid * 2 + 1] = fmaf(cb[co], sc, bnb[co]);
  }
  __syncthreads();

  const int w = tid >> 6, l = tid & 63, lr = l & 15, g = l >> 4;
  const int wp = w * 48;

  f32x4 acc[3][4];
  for (int m = 0; m < 3; ++m)
    for (int n = 0; n < 4; ++n)
      for (int i = 0; i < 4; ++i) acc[m][n][i] = 0.f;

  for (int chunk = 0; chunk < 4; ++chunk) {
    s16x8 wr[7];
    if (chunk < 3) {
      #pragma unroll
      for (int i = 0; i < 7; ++i) {
        int e = tid + i * 256;
        int co = e / 28, c = e % 28;
        wr[i] = *(const s16x8*)(w4p + (cg0 + co) * 896 + (chunk + 1) * 224 + c * 8);
      }
    }
    #pragma unroll
    for (int sl = 0; sl < 7; ++sl) {
      int k0 = chunk * 224 + sl * 32;
      int kk = k0 >> 7, cib = k0 & 127;
      s16x8 xa[3], wb[4];
      #pragma unroll
      for (int m = 0; m < 3; ++m) {
        int row = wp + m * 16 + lr + kk;
        xa[m] = *(const s16x8*)(lds + ((row * 256 + cib * 2 + g * 16) ^ ((row & 7) << 4)));
      }
      #pragma unroll
      for (int n = 0; n < 4; ++n) {
        int co = n * 16 + lr;
        wb[n] = *(const s16x8*)(lds + 50688 + ((co * 448 + sl * 64 + g * 16) ^ ((co & 7) << 4)));
      }
      #pragma unroll
      for (int m = 0; m < 3; ++m)
        #pragma unroll
        for (int n = 0; n < 4; ++n)
          acc[m][n] = __builtin_amdgcn_mfma_f32_16x16x32_bf16(xa[m], wb[n], acc[m][n], 0, 0, 0);
    }
    __syncthreads();
    if (chunk < 3) {
      #pragma unroll
      for (int i = 0; i < 7; ++i) {
        int e = tid + i * 256;
        int co = e / 28, c = e % 28;
        *(s16x8*)(lds + 50688 + ((co * 448 + c * 16) ^ ((co & 7) << 4))) = wr[i];
      }
    }
    __syncthreads();
  }

  float sc[4], sh[4];
  #pragma unroll
  for (int n = 0; n < 4; ++n) {
    sc[n] = scs[(n * 16 + lr) * 2];
    sh[n] = scs[(n * 16 + lr) * 2 + 1];
  }
  float psum[4] = {0.f, 0.f, 0.f, 0.f};
  #pragma unroll
  for (int m = 0; m < 3; ++m) {
    #pragma unroll
    for (int j = 0; j < 4; ++j) {
      int pos = wp + m * 16 + g * 4 + j;
      if (pos < 187) {
        #pragma unroll
        for (int n = 0; n < 4; ++n)
          psum[n] += fmaxf(fmaf(acc[m][n][j], sc[n], sh[n]), 0.f);
      }
    }
  }
  #pragma unroll
  for (int n = 0; n < 4; ++n) {
    float v = psum[n];
    v += __shfl_xor(v, 16);
    v += __shfl_xor(v, 32);
    if (l < 16)
      atomicAdd(&h4[b * 128 + cg0 + n * 16 + lr], v);
  }
}

// ---------------------------------------------------------------------------
// k_head2: 64 blocks x 256 thr, 4 batches/block.
// h4 -> fc -> ang -> embed (real product state) -> U_SEL * e -> probs -> z
// -> h1 -> h2 -> out
// ---------------------------------------------------------------------------
__global__ __launch_bounds__(256) void k_head2(
    const float* __restrict__ h4, const float* __restrict__ fc_wt,
    const float* __restrict__ fc_b, const float* __restrict__ ang_w,
    const float* __restrict__ ang_b, const float* __restrict__ h1_w,
    const float* __restrict__ h1_b, const float* __restrict__ h2_w,
    const float* __restrict__ h2_b, const float2* __restrict__ Ut,
    float* __restrict__ out)
{
  __shared__ float h4v[512];
  __shared__ float fvec[512];
  __shared__ float rcs[64];
  __shared__ float4 e4[256];
  __shared__ float4 parr[256];
  __shared__ float zsum[32];
  __shared__ float hh[256];

  const int tid = threadIdx.x;
  const int b0 = blockIdx.x * 4;

  #pragma unroll
  for (int q = 0; q < 2; ++q) {
    int task = tid + q * 256;
    h4v[task] = h4[(b0 + (task >> 7)) * 128 + (task & 127)] * (1.0f / 187.0f);
  }
  __syncthreads();

  #pragma unroll
  for (int q = 0; q < 2; ++q) {
    int task = tid + q * 256;
    int bb = task >> 7, o = task & 127;
    float a = fc_b[o];
    const float* hv = h4v + bb * 128;
    #pragma unroll 8
    for (int k = 0; k < 128; ++k) a = fmaf(hv[k], fc_wt[k * 128 + o], a);
    fvec[task] = fmaxf(a, 0.f);
  }
  __syncthreads();

  if (tid < 32) {
    int bb = tid >> 3, o = tid & 7;
    float a = ang_b[o];
    const float* fv = fvec + bb * 128;
    const float* wr = ang_w + o * 128;
    for (int k = 0; k < 128; ++k) a = fmaf(fv[k], wr[k], a);
    float ang = PI_F * tanhf(a);
    rcs[bb * 16 + o * 2]     = cosf(0.5f * ang);
    rcs[bb * 16 + o * 2 + 1] = sinf(0.5f * ang);
  }
  __syncthreads();

  {
    float4 ev;
    #pragma unroll
    for (int bb = 0; bb < 4; ++bb) {
      float prod = 1.f;
      #pragma unroll
      for (int w = 0; w < 8; ++w) {
        float cc = rcs[bb * 16 + w * 2];
        float ss = rcs[bb * 16 + w * 2 + 1];
        prod *= ((tid >> (7 - w)) & 1) ? ss : cc;
      }
      ev[bb] = prod;
    }
    e4[tid] = ev;
  }
  __syncthreads();

  {
    float ax0 = 0.f, ax1 = 0.f, ax2 = 0.f, ax3 = 0.f;
    float ay0 = 0.f, ay1 = 0.f, ay2 = 0.f, ay3 = 0.f;
    #pragma unroll 4
    for (int cc = 0; cc < 256; ++cc) {
      float2 u = Ut[cc * 256 + tid];
      float4 ev = e4[cc];
      ax0 = fmaf(u.x, ev[0], ax0); ay0 = fmaf(u.y, ev[0], ay0);
      ax1 = fmaf(u.x, ev[1], ax1); ay1 = fmaf(u.y, ev[1], ay1);
      ax2 = fmaf(u.x, ev[2], ax2); ay2 = fmaf(u.y, ev[2], ay2);
      ax3 = fmaf(u.x, ev[3], ax3); ay3 = fmaf(u.y, ev[3], ay3);
    }
    parr[tid] = make_float4(ax0 * ax0 + ay0 * ay0, ax1 * ax1 + ay1 * ay1,
                            ax2 * ax2 + ay2 * ay2, ax3 * ax3 + ay3 * ay3);
  }
  __syncthreads();

  {
    int task = tid >> 3, part = tid & 7;
    int bb = task >> 3, wq = task & 7;
    int bit = 7 - wq;
    float s = 0.f;
    #pragma unroll 8
    for (int i = 0; i < 32; ++i) {
      int row = i * 8 + part;
      const float* pr = (const float*)&parr[row];
      float p = pr[bb];
      s = ((row >> bit) & 1) ? (s - p) : (s + p);
    }
    s += __shfl_xor(s, 1);
    s += __shfl_xor(s, 2);
    s += __shfl_xor(s, 4);
    if (part == 0) zsum[task] = s;
  }
  __syncthreads();

  {
    int bb = tid >> 6, o = tid & 63;
    float a = h1_b[o];
    #pragma unroll
    for (int k = 0; k < 8; ++k) a = fmaf(zsum[bb * 8 + k], h1_w[o * 8 + k], a);
    hh[tid] = fmaxf(a, 0.f);
  }
  __syncthreads();

  if (tid < 20) {
    int bb = tid / 5, o = tid % 5;
    float a = h2_b[o];
    for (int j = 0; j < 64; ++j) a = fmaf(hh[bb * 64 + j], h2_w[o * 64 + j], a);
    out[(b0 + bb) * 5 + o] = a;
  }
}

// ---------------------------------------------------------------------------
extern "C" void kernel_launch(void* const* d_in, const int* in_sizes, int n_in,
                              void* d_out, int out_size, void* d_ws, size_t ws_size,
                              hipStream_t stream) {
  (void)in_sizes; (void)n_in; (void)out_size; (void)ws_size;
  const float* x    = (const float*)d_in[0];
  const float* c1w  = (const float*)d_in[1];
  const float* c1b  = (const float*)d_in[2];
  const float* b1g  = (const float*)d_in[3];
  const float* b1b  = (const float*)d_in[4];
  const float* c2w  = (const float*)d_in[5];
  const float* c2b  = (const float*)d_in[6];
  const float* b2g  = (const float*)d_in[7];
  const float* b2b  = (const float*)d_in[8];
  const float* c3w  = (const float*)d_in[9];
  const float* c3b  = (const float*)d_in[10];
  const float* b3g  = (const float*)d_in[11];
  const float* b3b  = (const float*)d_in[12];
  const float* c4w  = (const float*)d_in[13];
  const float* c4b  = (const float*)d_in[14];
  const float* b4g  = (const float*)d_in[15];
  const float* b4b  = (const float*)d_in[16];
  const float* fcw  = (const float*)d_in[17];
  const float* fcb  = (const float*)d_in[18];
  const float* angw = (const float*)d_in[19];
  const float* angb = (const float*)d_in[20];
  const float* qw   = (const float*)d_in[21];
  const float* h1w  = (const float*)d_in[22];
  const float* h1b  = (const float*)d_in[23];
  const float* h2w  = (const float*)d_in[24];
  const float* h2b  = (const float*)d_in[25];

  char* wsb = (char*)d_ws;
  unsigned short* w1p  = (unsigned short*)(wsb + 0);        // 4096 B
  unsigned short* w2p  = (unsigned short*)(wsb + 4096);     // 28672 B
  unsigned short* w3p  = (unsigned short*)(wsb + 32768);    // 114688 B
  unsigned short* w4p  = (unsigned short*)(wsb + 147456);   // 229376 B
  float*          h4   = (float*)(wsb + 393216);            // 131072 B
  unsigned short* h2pt = (unsigned short*)(wsb + 52428800); // 24.58 MB
  unsigned short* h3pt = (unsigned short*)(wsb + 79691776); // 12.25 MB
  float2*         Ut   = (float2*)(wsb + 100663296);        // 524288 B
  float*          fcwt = (float*)(wsb + 101187584);         // 65536 B

  k_packumat<<<dim3(944), 256, 0, stream>>>(c1w, c2w, c3w, c4w, fcw, qw,
                                            w1p, w2p, w3p, w4p, fcwt, h4, Ut);
  k_conv12<<<dim3(12, 256), 256, 0, stream>>>(x, w1p, w2p, c1b, b1g, b1b,
                                              c2b, b2g, b2b, h2pt);
  k_conv3<<<dim3(6, 256), 256, 0, stream>>>(h2pt, w3p, c3b, b3g, b3b, h3pt);
  k_conv4<<<dim3(2, 256), 256, 0, stream>>>(h3pt, w4p, c4b, b4g, b4b, h4);
  k_head2<<<dim3(64), 256, 0, stream>>>(h4, fcwt, fcb, angw, angb,
                                        h1w, h1b, h2w, h2b, Ut, (float*)d_out);
}

// Round 8
// 229.752 us; speedup vs baseline: 1.0792x; 1.0318x over previous
//
#include <hip/hip_runtime.h>
#include <hip/hip_bf16.h>

#define BN_INV 0.9999950000375f   // 1/sqrt(1+1e-5)
#define PI_F   3.14159265358979f

typedef __attribute__((ext_vector_type(8))) short s16x8;
typedef __attribute__((ext_vector_type(4))) float f32x4;
typedef __attribute__((ext_vector_type(4))) unsigned short u16x4;

__device__ inline unsigned short f2bf(float f) {
  union { float f; unsigned u; } v; v.f = f;
  unsigned r = v.u + 0x7fffu + ((v.u >> 16) & 1u);
  return (unsigned short)(r >> 16);
}

// ---------------------------------------------------------------------------
// k_packumat: blocks 0..927 = weight pack (+h4 zero, fc transpose);
// blocks 928..943 = build U_SEL (fixed 256x256 SEL unitary), Ut[col][row]
// ---------------------------------------------------------------------------
__global__ __launch_bounds__(256) void k_packumat(
    const float* __restrict__ w1, const float* __restrict__ w2,
    const float* __restrict__ w3, const float* __restrict__ w4,
    const float* __restrict__ fcw, const float* __restrict__ qw,
    unsigned short* __restrict__ w1p, unsigned short* __restrict__ w2p,
    unsigned short* __restrict__ w3p, unsigned short* __restrict__ w4p,
    float* __restrict__ fcwt, float* __restrict__ h4,
    float2* __restrict__ Ut)
{
  __shared__ float rotm[16][8];
  const int tid = threadIdx.x;

  if (blockIdx.x < 928) {
    int e = blockIdx.x * 256 + tid;
    if (e < 2048) {
      int co = e >> 6, k = e & 63, kk = k >> 3, ci = k & 7;
      w1p[e] = (ci < 4 && kk < 7) ? f2bf(w1[co * 28 + ci * 7 + kk]) : (unsigned short)0;
    } else if (e < 16384) {
      int t = e - 2048; int co = t / 224, k = t % 224, kk = k >> 5, ci = k & 31;
      w2p[t] = f2bf(w2[co * 224 + ci * 7 + kk]);
    } else if (e < 73728) {
      int t = e - 16384; int co = t / 448, k = t % 448, kk = k >> 6, ci = k & 63;
      w3p[t] = f2bf(w3[co * 448 + ci * 7 + kk]);
    } else if (e < 188416) {
      int t = e - 73728; int co = t / 896, k = t % 896, kk = k >> 7, ci = k & 127;
      w4p[t] = f2bf(w4[co * 896 + ci * 7 + kk]);
    } else if (e < 221184) {
      h4[e - 188416] = 0.f;
    } else if (e < 237568) {
      int t = e - 221184; int k = t >> 7, o = t & 127;
      fcwt[t] = fcw[o * 128 + k];
    }
    return;
  }

  // ---- umat path ----
  const int bx = blockIdx.x - 928;
  if (tid < 16) {
    int gq = tid;
    float phi = qw[gq * 3], th = qw[gq * 3 + 1], om = qw[gq * 3 + 2];
    float cm = cosf(0.5f * th), sm = sinf(0.5f * th);
    float ap = 0.5f * (phi + om), bm = 0.5f * (phi - om);
    rotm[gq][0] = cm * cosf(ap);  rotm[gq][1] = -cm * sinf(ap);
    rotm[gq][2] = -sm * cosf(bm); rotm[gq][3] = -sm * sinf(bm);
    rotm[gq][4] = sm * cosf(bm);  rotm[gq][5] = -sm * sinf(bm);
    rotm[gq][6] = cm * cosf(ap);  rotm[gq][7] = cm * sinf(ap);
  }
  __syncthreads();

  const int lane = tid & 63, wid = tid >> 6;
  const int ll = lane & 15;
  const int c = (bx * 4 + wid) * 4 + (lane >> 4);

  float2 st[16];
  #pragma unroll
  for (int r = 0; r < 16; ++r) {
    st[r].x = (ll == (c >> 4) && r == (c & 15)) ? 1.f : 0.f;
    st[r].y = 0.f;
  }

#define LOADM(G) \
  float m00x = rotm[G][0], m00y = rotm[G][1], m01x = rotm[G][2], m01y = rotm[G][3], \
        m10x = rotm[G][4], m10y = rotm[G][5], m11x = rotm[G][6], m11y = rotm[G][7];

#define ROT_REG(G, BETA) { LOADM(G) \
  _Pragma("unroll") \
  for (int r = 0; r < 16; ++r) if (!(r & BETA)) { \
    float2 A = st[r], B = st[r + BETA]; \
    st[r].x = m00x*A.x - m00y*A.y + m01x*B.x - m01y*B.y; \
    st[r].y = m00x*A.y + m00y*A.x + m01x*B.y + m01y*B.x; \
    st[r+BETA].x = m10x*A.x - m10y*A.y + m11x*B.x - m11y*B.y; \
    st[r+BETA].y = m10x*A.y + m10y*A.x + m11x*B.y + m11y*B.x; } }

#define ROT_LANE(G, LX) { LOADM(G) \
  _Pragma("unroll") \
  for (int r = 0; r < 16; ++r) { \
    float ox = __shfl_xor(st[r].x, LX); \
    float oy = __shfl_xor(st[r].y, LX); \
    bool hi = (lane & LX) != 0; \
    float a0x = hi ? ox : st[r].x, a0y = hi ? oy : st[r].y; \
    float a1x = hi ? st[r].x : ox, a1y = hi ? st[r].y : oy; \
    float cx = hi ? m10x : m00x, cy = hi ? m10y : m00y; \
    float dx = hi ? m11x : m01x, dy = hi ? m11y : m01y; \
    st[r].x = cx*a0x - cy*a0y + dx*a1x - dy*a1y; \
    st[r].y = cx*a0y + cy*a0x + dx*a1y + dy*a1x; } }

#define CNOT_RR(BC, BT) { \
  _Pragma("unroll") \
  for (int r = 0; r < 16; ++r) if ((r & BC) && !(r & BT)) { \
    float2 t_ = st[r]; st[r] = st[r + BT]; st[r + BT] = t_; } }

#define CNOT_RL(BC, LXT) { \
  _Pragma("unroll") \
  for (int r = 0; r < 16; ++r) if (r & BC) { \
    st[r].x = __shfl_xor(st[r].x, LXT); \
    st[r].y = __shfl_xor(st[r].y, LXT); } }

#define CNOT_LR(LXC, BT) { bool cc = (lane & LXC) != 0; \
  _Pragma("unroll") \
  for (int r = 0; r < 16; ++r) if (!(r & BT)) { \
    float2 A = st[r], B = st[r + BT]; \
    st[r].x = cc ? B.x : A.x;  st[r].y = cc ? B.y : A.y; \
    st[r+BT].x = cc ? A.x : B.x;  st[r+BT].y = cc ? A.y : B.y; } }

#define CNOT_LL(LXC, LXT) { bool cc = (lane & LXC) != 0; \
  _Pragma("unroll") \
  for (int r = 0; r < 16; ++r) { \
    float ox = __shfl_xor(st[r].x, LXT); \
    float oy = __shfl_xor(st[r].y, LXT); \
    if (cc) { st[r].x = ox; st[r].y = oy; } } }

  // layer 0: Rot wires 0..7; CNOT ring r=1
  ROT_LANE(0, 8) ROT_LANE(1, 4) ROT_LANE(2, 2) ROT_LANE(3, 1)
  ROT_REG(4, 8)  ROT_REG(5, 4)  ROT_REG(6, 2)  ROT_REG(7, 1)
  CNOT_LL(8, 4) CNOT_LL(4, 2) CNOT_LL(2, 1) CNOT_LR(1, 8)
  CNOT_RR(8, 4) CNOT_RR(4, 2) CNOT_RR(2, 1) CNOT_RL(1, 8)
  // layer 1: Rot wires 0..7; CNOT ring r=2
  ROT_LANE(8, 8) ROT_LANE(9, 4) ROT_LANE(10, 2) ROT_LANE(11, 1)
  ROT_REG(12, 8) ROT_REG(13, 4) ROT_REG(14, 2)  ROT_REG(15, 1)
  CNOT_LL(8, 2) CNOT_LL(4, 1) CNOT_LR(2, 8) CNOT_LR(1, 4)
  CNOT_RR(8, 2) CNOT_RR(4, 1) CNOT_RL(2, 8) CNOT_RL(1, 4)

#undef LOADM
#undef ROT_REG
#undef ROT_LANE
#undef CNOT_RR
#undef CNOT_RL
#undef CNOT_LR
#undef CNOT_LL

  float2* uc = Ut + c * 256 + ll * 16;
  #pragma unroll
  for (int r = 0; r < 16; r += 2) {
    float4 v = make_float4(st[r].x, st[r].y, st[r + 1].x, st[r + 1].y);
    *(float4*)(uc + r) = v;
  }
}

// ---------------------------------------------------------------------------
// k_conv12 v2: fused conv1+conv2, 512 threads, pos512/block, grid (6,256)
// Phase A: stage x raw (536 rows x 16B), compute h1 rows 0..517 via MFMA
//   into LDS (conv2 x-layout, swizzled).
// Phase B: proven conv2 (wave = pos64(4m) x co64(4n), K=224) -> h2pt.
// LDS 71296 B -> 2 blocks/CU (16 waves/CU).
// ---------------------------------------------------------------------------
__global__ __launch_bounds__(512) void k_conv12(
    const float* __restrict__ x, const unsigned short* __restrict__ w1p,
    const unsigned short* __restrict__ w2p,
    const float* __restrict__ c1b, const float* __restrict__ b1g,
    const float* __restrict__ b1b,
    const float* __restrict__ c2b, const float* __restrict__ b2g,
    const float* __restrict__ b2b,
    unsigned short* __restrict__ h2pt)
{
  __shared__ __align__(16) char lds[71296];
  const int XR = 0;          // x raw: 536 rows x 16B = 8576
  const int H1 = 8576;       // h1 tile: 520 rows x 64B = 33280
  const int W2 = 41856;      // conv2 weights: 28672
  float* s1 = (float*)(lds + 70528);  // 32 co x {scale, shift}
  float* s2 = (float*)(lds + 70784);  // 64 co x {scale, shift}

  const int tid = threadIdx.x, b = blockIdx.y;
  const int l0 = blockIdx.x * 512;

  // stage x raw: row r <-> global pos l0-6+r; rows >=524 zero (pad taps)
  for (int r = tid; r < 536; r += 512) {
    int gp = l0 - 6 + r;
    s16x8 v;
    for (int i = 0; i < 8; ++i) v[i] = 0;
    if (r < 524 && gp >= 0 && gp < 3000) {
      const float* xr = x + b * 4 * 3000 + gp;
      v[0] = (short)f2bf(xr[0]);
      v[1] = (short)f2bf(xr[3000]);
      v[2] = (short)f2bf(xr[6000]);
      v[3] = (short)f2bf(xr[9000]);
    }
    *(s16x8*)(lds + XR + r * 16) = v;
  }
  for (int e = tid; e < 1792; e += 512) {  // conv2 weights: 64co x 28 chunks
    int co = e / 28, cc = e % 28;
    s16x8 v = *(const s16x8*)(w2p + co * 224 + cc * 8);
    *(s16x8*)(lds + W2 + ((co * 448 + cc * 16) ^ ((co & 7) << 4))) = v;
  }
  if (tid < 32) {
    float sc = b1g[tid] * BN_INV;
    s1[tid * 2] = sc;
    s1[tid * 2 + 1] = fmaf(c1b[tid], sc, b1b[tid]);
  }
  if (tid < 64) {
    float sc = b2g[tid] * BN_INV;
    s2[tid * 2] = sc;
    s2[tid * 2 + 1] = fmaf(c2b[tid], sc, b2b[tid]);
  }
  __syncthreads();

  const int w = tid >> 6, lane = tid & 63, lr = lane & 15, g = lane >> 4;

  // ---- Phase A: conv1 -> h1 LDS tile (33 tiles over 8 waves) ----
  {
    s16x8 a1[2][2];
    #pragma unroll
    for (int m = 0; m < 2; ++m)
      #pragma unroll
      for (int s = 0; s < 2; ++s)
        a1[m][s] = *(const s16x8*)(w1p + (m * 16 + lr) * 64 + s * 32 + g * 8);

    #pragma unroll
    for (int t = 0; t < 5; ++t) {
      int tile = w + t * 8;             // 33 tiles cover 528 >= 518 rows
      if (tile >= 33) break;
      int p0 = tile * 16;
      f32x4 acc[2];
      for (int m = 0; m < 2; ++m)
        for (int i = 0; i < 4; ++i) acc[m][i] = 0.f;
      #pragma unroll
      for (int s = 0; s < 2; ++s) {
        s16x8 bf = *(const s16x8*)(lds + XR + (p0 + lr + s * 4 + g) * 16);
        acc[0] = __builtin_amdgcn_mfma_f32_16x16x32_bf16(a1[0][s], bf, acc[0], 0, 0, 0);
        acc[1] = __builtin_amdgcn_mfma_f32_16x16x32_bf16(a1[1][s], bf, acc[1], 0, 0, 0);
      }
      int r2 = p0 + lr;                 // h1 tile row (pos l0 + r2 - 3)
      if (r2 < 518) {
        #pragma unroll
        for (int m = 0; m < 2; ++m) {
          int co0 = m * 16 + g * 4;
          u16x4 o;
          #pragma unroll
          for (int j = 0; j < 4; ++j)
            o[j] = f2bf(fmaxf(fmaf(acc[m][j], s1[(co0 + j) * 2], s1[(co0 + j) * 2 + 1]), 0.f));
          int byte = ((r2 * 64 + (co0 >> 3) * 16) ^ ((r2 & 7) << 4)) + (co0 & 7) * 2;
          *(u16x4*)(lds + H1 + byte) = o;
        }
      }
    }
  }
  __syncthreads();

  // ---- Phase B: conv2 + pool4 (proven structure) ----
  const int wp = w * 64;
  f32x4 acc[4][4];
  for (int m = 0; m < 4; ++m)
    for (int n = 0; n < 4; ++n)
      for (int i = 0; i < 4; ++i) acc[m][n][i] = 0.f;

  #pragma unroll
  for (int s = 0; s < 7; ++s) {
    s16x8 xa[4], wb[4];
    #pragma unroll
    for (int m = 0; m < 4; ++m) {
      int row = wp + m * 16 + lr + s;
      xa[m] = *(const s16x8*)(lds + H1 + ((row * 64 + g * 16) ^ ((row & 7) << 4)));
    }
    #pragma unroll
    for (int n = 0; n < 4; ++n) {
      int co = n * 16 + lr;
      wb[n] = *(const s16x8*)(lds + W2 + ((co * 448 + s * 64 + g * 16) ^ ((co & 7) << 4)));
    }
    #pragma unroll
    for (int m = 0; m < 4; ++m)
      #pragma unroll
      for (int n = 0; n < 4; ++n)
        acc[m][n] = __builtin_amdgcn_mfma_f32_16x16x32_bf16(xa[m], wb[n], acc[m][n], 0, 0, 0);
  }

  float sc[4], sh[4];
  #pragma unroll
  for (int n = 0; n < 4; ++n) {
    sc[n] = s2[(n * 16 + lr) * 2];
    sh[n] = s2[(n * 16 + lr) * 2 + 1];
  }
  #pragma unroll
  for (int m = 0; m < 4; ++m) {
    int pp = (l0 + wp + m * 16 + g * 4) >> 2;
    if (pp < 750) {
      unsigned short* orow = h2pt + (b * 750 + pp) * 64 + lr;
      #pragma unroll
      for (int n = 0; n < 4; ++n) {
        float v = fmaxf(fmaxf(acc[m][n][0], acc[m][n][1]),
                        fmaxf(acc[m][n][2], acc[m][n][3]));
        orow[n * 16] = f2bf(fmaxf(fmaf(v, sc[n], sh[n]), 0.f));
      }
    }
  }
}

// ---------------------------------------------------------------------------
// conv3 v2: pos128 x co128 block; wave = pos64(4m) x co64(4n); K=448, 2 chunks
// T14 reg-prefetch of chunk 1 weights. grid (6, 256)
// ---------------------------------------------------------------------------
__global__ __launch_bounds__(256) void k_conv3(
    const unsigned short* __restrict__ h2pt, const unsigned short* __restrict__ w3p,
    const float* __restrict__ cb, const float* __restrict__ bng,
    const float* __restrict__ bnb, unsigned short* __restrict__ h3pt)
{
  __shared__ __align__(16) char lds[75776];
  float* scs = (float*)(lds + 74752);
  const int tid = threadIdx.x, b = blockIdx.y;
  const int l0 = blockIdx.x * 128;

  for (int e = tid; e < 1072; e += 256) {  // x: 134 rows x 8 chunks
    int r = e >> 3, c = e & 7;
    int gr = l0 + r - 3;
    s16x8 v;
    if (gr >= 0 && gr < 750) v = *(const s16x8*)(h2pt + (b * 750 + gr) * 64 + c * 8);
    else for (int i = 0; i < 8; ++i) v[i] = 0;
    *(s16x8*)(lds + ((r * 128 + c * 16) ^ ((r & 7) << 4))) = v;
  }
  for (int e = tid; e < 3584; e += 256) {  // weights chunk 0: 128co x 28 chunks
    int co = e / 28, c = e % 28;
    s16x8 v = *(const s16x8*)(w3p + co * 448 + c * 8);
    *(s16x8*)(lds + 17408 + ((co * 448 + c * 16) ^ ((co & 7) << 4))) = v;
  }
  if (tid < 128) {
    float sc = bng[tid] * BN_INV;
    scs[tid * 2] = sc;
    scs[tid * 2 + 1] = fmaf(cb[tid], sc, bnb[tid]);
  }

  const int lane = tid & 63, wid = tid >> 6;
  const int wr = wid >> 1, wc = wid & 1;
  const int lr = lane & 15, g = lane >> 4;

  f32x4 acc[4][4];
  for (int m = 0; m < 4; ++m)
    for (int n = 0; n < 4; ++n)
      for (int i = 0; i < 4; ++i) acc[m][n][i] = 0.f;

  s16x8 pw[14];  // T14: prefetch chunk-1 weights
  #pragma unroll
  for (int i = 0; i < 14; ++i) {
    int e = tid + i * 256;
    int co = e / 28, c = e % 28;
    pw[i] = *(const s16x8*)(w3p + co * 448 + 224 + c * 8);
  }
  __syncthreads();

  for (int chunk = 0; chunk < 2; ++chunk) {
    #pragma unroll
    for (int sl = 0; sl < 7; ++sl) {
      int k0 = chunk * 224 + sl * 32;
      int kk = k0 >> 6, cib = k0 & 63;
      s16x8 xa[4], wb[4];
      #pragma unroll
      for (int m = 0; m < 4; ++m) {
        int row = wr * 64 + m * 16 + lr + kk;
        xa[m] = *(const s16x8*)(lds + ((row * 128 + cib * 2 + g * 16) ^ ((row & 7) << 4)));
      }
      #pragma unroll
      for (int n = 0; n < 4; ++n) {
        int co = wc * 64 + n * 16 + lr;
        wb[n] = *(const s16x8*)(lds + 17408 + ((co * 448 + sl * 64 + g * 16) ^ ((co & 7) << 4)));
      }
      #pragma unroll
      for (int m = 0; m < 4; ++m)
        #pragma unroll
        for (int n = 0; n < 4; ++n)
          acc[m][n] = __builtin_amdgcn_mfma_f32_16x16x32_bf16(xa[m], wb[n], acc[m][n], 0, 0, 0);
    }
    if (chunk == 0) {
      __syncthreads();
      #pragma unroll
      for (int i = 0; i < 14; ++i) {
        int e = tid + i * 256;
        int co = e / 28, c = e % 28;
        *(s16x8*)(lds + 17408 + ((co * 448 + c * 16) ^ ((co & 7) << 4))) = pw[i];
      }
      __syncthreads();
    }
  }

  float sc[4], sh[4];
  #pragma unroll
  for (int n = 0; n < 4; ++n) {
    int co = wc * 64 + n * 16 + lr;
    sc[n] = scs[co * 2];
    sh[n] = scs[co * 2 + 1];
  }
  #pragma unroll
  for (int m = 0; m < 4; ++m) {
    int pp = (l0 + wr * 64 + m * 16 + g * 4) >> 2;
    if (pp < 187) {
      unsigned short* orow = h3pt + (b * 187 + pp) * 128;
      #pragma unroll
      for (int n = 0; n < 4; ++n) {
        int co = wc * 64 + n * 16 + lr;
        float v = fmaxf(fmaxf(acc[m][n][0], acc[m][n][1]),
                        fmaxf(acc[m][n][2], acc[m][n][3]));
        orow[co] = f2bf(fmaxf(fmaf(v, sc[n], sh[n]), 0.f));
      }
    }
  }
}

// ---------------------------------------------------------------------------
// conv4 (operand-swapped): h3pt -> BN+ReLU -> masked mean -> atomicAdd h4
// ---------------------------------------------------------------------------
__global__ __launch_bounds__(256) void k_conv4(
    const unsigned short* __restrict__ h3pt, const unsigned short* __restrict__ w4p,
    const float* __restrict__ cb, const float* __restrict__ bng,
    const float* __restrict__ bnb, float* __restrict__ h4)
{
  __shared__ __align__(16) char lds[79872];
  float* scs = (float*)(lds + 79360);
  const int tid = threadIdx.x, b = blockIdx.y, ch = blockIdx.x;
  const int cg0 = ch * 64;

  #pragma unroll
  for (int i = 0; i < 13; ++i) {  // x: 198 rows x 16 chunks
    int e = tid + i * 256;
    if (e < 3168) {
      int r = e >> 4, c = e & 15, gr = r - 3;
      s16x8 v;
      if (gr >= 0 && gr < 187) v = *(const s16x8*)(h3pt + (b * 187 + gr) * 128 + c * 8);
      else for (int q = 0; q < 8; ++q) v[q] = 0;
      *(s16x8*)(lds + ((r * 256 + c * 16) ^ ((r & 7) << 4))) = v;
    }
  }
  for (int e = tid; e < 1792; e += 256) {  // weight chunk 0
    int co = e / 28, c = e % 28;
    s16x8 v = *(const s16x8*)(w4p + (cg0 + co) * 896 + c * 8);
    *(s16x8*)(lds + 50688 + ((co * 448 + c * 16) ^ ((co & 7) << 4))) = v;
  }
  if (tid < 64) {
    int co = cg0 + tid;
    float sc = bng[co] * BN_INV;
    scs[tid * 2] = sc;
    scs[tid * 2 + 1] = fmaf(cb[co], sc, bnb[co]);
  }
  __syncthreads();

  const int w = tid >> 6, l = tid & 63, lr = l & 15, g = l >> 4;
  const int wp = w * 48;

  f32x4 acc[3][4];
  for (int m = 0; m < 3; ++m)
    for (int n = 0; n < 4; ++n)
      for (int i = 0; i < 4; ++i) acc[m][n][i] = 0.f;

  for (int chunk = 0; chunk < 4; ++chunk) {
    s16x8 wr[7];
    if (chunk < 3) {
      #pragma unroll
      for (int i = 0; i < 7; ++i) {
        int e = tid + i * 256;
        int co = e / 28, c = e % 28;
        wr[i] = *(const s16x8*)(w4p + (cg0 + co) * 896 + (chunk + 1) * 224 + c * 8);
      }
    }
    #pragma unroll
    for (int sl = 0; sl < 7; ++sl) {
      int k0 = chunk * 224 + sl * 32;
      int kk = k0 >> 7, cib = k0 & 127;
      s16x8 xa[3], wb[4];
      #pragma unroll
      for (int m = 0; m < 3; ++m) {
        int row = wp + m * 16 + lr + kk;
        xa[m] = *(const s16x8*)(lds + ((row * 256 + cib * 2 + g * 16) ^ ((row & 7) << 4)));
      }
      #pragma unroll
      for (int n = 0; n < 4; ++n) {
        int co = n * 16 + lr;
        wb[n] = *(const s16x8*)(lds + 50688 + ((co * 448 + sl * 64 + g * 16) ^ ((co & 7) << 4)));
      }
      #pragma unroll
      for (int m = 0; m < 3; ++m)
        #pragma unroll
        for (int n = 0; n < 4; ++n)
          acc[m][n] = __builtin_amdgcn_mfma_f32_16x16x32_bf16(xa[m], wb[n], acc[m][n], 0, 0, 0);
    }
    __syncthreads();
    if (chunk < 3) {
      #pragma unroll
      for (int i = 0; i < 7; ++i) {
        int e = tid + i * 256;
        int co = e / 28, c = e % 28;
        *(s16x8*)(lds + 50688 + ((co * 448 + c * 16) ^ ((co & 7) << 4))) = wr[i];
      }
    }
    __syncthreads();
  }

  float sc[4], sh[4];
  #pragma unroll
  for (int n = 0; n < 4; ++n) {
    sc[n] = scs[(n * 16 + lr) * 2];
    sh[n] = scs[(n * 16 + lr) * 2 + 1];
  }
  float psum[4] = {0.f, 0.f, 0.f, 0.f};
  #pragma unroll
  for (int m = 0; m < 3; ++m) {
    #pragma unroll
    for (int j = 0; j < 4; ++j) {
      int pos = wp + m * 16 + g * 4 + j;
      if (pos < 187) {
        #pragma unroll
        for (int n = 0; n < 4; ++n)
          psum[n] += fmaxf(fmaf(acc[m][n][j], sc[n], sh[n]), 0.f);
      }
    }
  }
  #pragma unroll
  for (int n = 0; n < 4; ++n) {
    float v = psum[n];
    v += __shfl_xor(v, 16);
    v += __shfl_xor(v, 32);
    if (l < 16)
      atomicAdd(&h4[b * 128 + cg0 + n * 16 + lr], v);
  }
}

// ---------------------------------------------------------------------------
// k_head2: 64 blocks x 256 thr, 4 batches/block.
// h4 -> fc -> ang -> embed (real product state) -> U_SEL * e -> probs -> z
// -> h1 -> h2 -> out
// ---------------------------------------------------------------------------
__global__ __launch_bounds__(256) void k_head2(
    const float* __restrict__ h4, const float* __restrict__ fc_wt,
    const float* __restrict__ fc_b, const float* __restrict__ ang_w,
    const float* __restrict__ ang_b, const float* __restrict__ h1_w,
    const float* __restrict__ h1_b, const float* __restrict__ h2_w,
    const float* __restrict__ h2_b, const float2* __restrict__ Ut,
    float* __restrict__ out)
{
  __shared__ float h4v[512];
  __shared__ float fvec[512];
  __shared__ float rcs[64];
  __shared__ float4 e4[256];
  __shared__ float4 parr[256];
  __shared__ float zsum[32];
  __shared__ float hh[256];

  const int tid = threadIdx.x;
  const int b0 = blockIdx.x * 4;

  #pragma unroll
  for (int q = 0; q < 2; ++q) {
    int task = tid + q * 256;
    h4v[task] = h4[(b0 + (task >> 7)) * 128 + (task & 127)] * (1.0f / 187.0f);
  }
  __syncthreads();

  #pragma unroll
  for (int q = 0; q < 2; ++q) {
    int task = tid + q * 256;
    int bb = task >> 7, o = task & 127;
    float a = fc_b[o];
    const float* hv = h4v + bb * 128;
    #pragma unroll 8
    for (int k = 0; k < 128; ++k) a = fmaf(hv[k], fc_wt[k * 128 + o], a);
    fvec[task] = fmaxf(a, 0.f);
  }
  __syncthreads();

  if (tid < 32) {
    int bb = tid >> 3, o = tid & 7;
    float a = ang_b[o];
    const float* fv = fvec + bb * 128;
    const float* wr = ang_w + o * 128;
    for (int k = 0; k < 128; ++k) a = fmaf(fv[k], wr[k], a);
    float ang = PI_F * tanhf(a);
    rcs[bb * 16 + o * 2]     = cosf(0.5f * ang);
    rcs[bb * 16 + o * 2 + 1] = sinf(0.5f * ang);
  }
  __syncthreads();

  {
    float4 ev;
    #pragma unroll
    for (int bb = 0; bb < 4; ++bb) {
      float prod = 1.f;
      #pragma unroll
      for (int w = 0; w < 8; ++w) {
        float cc = rcs[bb * 16 + w * 2];
        float ss = rcs[bb * 16 + w * 2 + 1];
        prod *= ((tid >> (7 - w)) & 1) ? ss : cc;
      }
      ev[bb] = prod;
    }
    e4[tid] = ev;
  }
  __syncthreads();

  {
    float ax0 = 0.f, ax1 = 0.f, ax2 = 0.f, ax3 = 0.f;
    float ay0 = 0.f, ay1 = 0.f, ay2 = 0.f, ay3 = 0.f;
    #pragma unroll 4
    for (int cc = 0; cc < 256; ++cc) {
      float2 u = Ut[cc * 256 + tid];
      float4 ev = e4[cc];
      ax0 = fmaf(u.x, ev[0], ax0); ay0 = fmaf(u.y, ev[0], ay0);
      ax1 = fmaf(u.x, ev[1], ax1); ay1 = fmaf(u.y, ev[1], ay1);
      ax2 = fmaf(u.x, ev[2], ax2); ay2 = fmaf(u.y, ev[2], ay2);
      ax3 = fmaf(u.x, ev[3], ax3); ay3 = fmaf(u.y, ev[3], ay3);
    }
    parr[tid] = make_float4(ax0 * ax0 + ay0 * ay0, ax1 * ax1 + ay1 * ay1,
                            ax2 * ax2 + ay2 * ay2, ax3 * ax3 + ay3 * ay3);
  }
  __syncthreads();

  {
    int task = tid >> 3, part = tid & 7;
    int bb = task >> 3, wq = task & 7;
    int bit = 7 - wq;
    float s = 0.f;
    #pragma unroll 8
    for (int i = 0; i < 32; ++i) {
      int row = i * 8 + part;
      const float* pr = (const float*)&parr[row];
      float p = pr[bb];
      s = ((row >> bit) & 1) ? (s - p) : (s + p);
    }
    s += __shfl_xor(s, 1);
    s += __shfl_xor(s, 2);
    s += __shfl_xor(s, 4);
    if (part == 0) zsum[task] = s;
  }
  __syncthreads();

  {
    int bb = tid >> 6, o = tid & 63;
    float a = h1_b[o];
    #pragma unroll
    for (int k = 0; k < 8; ++k) a = fmaf(zsum[bb * 8 + k], h1_w[o * 8 + k], a);
    hh[tid] = fmaxf(a, 0.f);
  }
  __syncthreads();

  if (tid < 20) {
    int bb = tid / 5, o = tid % 5;
    float a = h2_b[o];
    for (int j = 0; j < 64; ++j) a = fmaf(hh[bb * 64 + j], h2_w[o * 64 + j], a);
    out[(b0 + bb) * 5 + o] = a;
  }
}

// ---------------------------------------------------------------------------
extern "C" void kernel_launch(void* const* d_in, const int* in_sizes, int n_in,
                              void* d_out, int out_size, void* d_ws, size_t ws_size,
                              hipStream_t stream) {
  (void)in_sizes; (void)n_in; (void)out_size; (void)ws_size;
  const float* x    = (const float*)d_in[0];
  const float* c1w  = (const float*)d_in[1];
  const float* c1b  = (const float*)d_in[2];
  const float* b1g  = (const float*)d_in[3];
  const float* b1b  = (const float*)d_in[4];
  const float* c2w  = (const float*)d_in[5];
  const float* c2b  = (const float*)d_in[6];
  const float* b2g  = (const float*)d_in[7];
  const float* b2b  = (const float*)d_in[8];
  const float* c3w  = (const float*)d_in[9];
  const float* c3b  = (const float*)d_in[10];
  const float* b3g  = (const float*)d_in[11];
  const float* b3b  = (const float*)d_in[12];
  const float* c4w  = (const float*)d_in[13];
  const float* c4b  = (const float*)d_in[14];
  const float* b4g  = (const float*)d_in[15];
  const float* b4b  = (const float*)d_in[16];
  const float* fcw  = (const float*)d_in[17];
  const float* fcb  = (const float*)d_in[18];
  const float* angw = (const float*)d_in[19];
  const float* angb = (const float*)d_in[20];
  const float* qw   = (const float*)d_in[21];
  const float* h1w  = (const float*)d_in[22];
  const float* h1b  = (const float*)d_in[23];
  const float* h2w  = (const float*)d_in[24];
  const float* h2b  = (const float*)d_in[25];

  char* wsb = (char*)d_ws;
  unsigned short* w1p  = (unsigned short*)(wsb + 0);        // 4096 B
  unsigned short* w2p  = (unsigned short*)(wsb + 4096);     // 28672 B
  unsigned short* w3p  = (unsigned short*)(wsb + 32768);    // 114688 B
  unsigned short* w4p  = (unsigned short*)(wsb + 147456);   // 229376 B
  float*          h4   = (float*)(wsb + 393216);            // 131072 B
  unsigned short* h2pt = (unsigned short*)(wsb + 52428800); // 24.58 MB
  unsigned short* h3pt = (unsigned short*)(wsb + 79691776); // 12.25 MB
  float2*         Ut   = (float2*)(wsb + 100663296);        // 524288 B
  float*          fcwt = (float*)(wsb + 101187584);         // 65536 B

  k_packumat<<<dim3(944), 256, 0, stream>>>(c1w, c2w, c3w, c4w, fcw, qw,
                                            w1p, w2p, w3p, w4p, fcwt, h4, Ut);
  k_conv12<<<dim3(6, 256), 512, 0, stream>>>(x, w1p, w2p, c1b, b1g, b1b,
                                             c2b, b2g, b2b, h2pt);
  k_conv3<<<dim3(6, 256), 256, 0, stream>>>(h2pt, w3p, c3b, b3g, b3b, h3pt);
  k_conv4<<<dim3(2, 256), 256, 0, stream>>>(h3pt, w4p, c4b, b4g, b4b, h4);
  k_head2<<<dim3(64), 256, 0, stream>>>(h4, fcwt, fcb, angw, angb,
                                        h1w, h1b, h2w, h2b, Ut, (float*)d_out);
}